// Round 12
// baseline (483.352 us; speedup 1.0000x reference)
//
#include <hip/hip_runtime.h>
#include <hip/hip_bf16.h>

typedef unsigned short u16;
typedef __attribute__((ext_vector_type(8))) short bf8_t;   // 8 bf16 (4 VGPR) MFMA A/B frag
typedef __attribute__((ext_vector_type(4))) float f4_t;    // MFMA C/D frag (16x16)
typedef __attribute__((ext_vector_type(16))) float fx16;   // MFMA C/D frag (32x32)

__device__ __forceinline__ float bf2f(u16 v) {
    union { unsigned u; float f; } c; c.u = ((unsigned)v) << 16; return c.f;
}
__device__ __forceinline__ u16 f2bf(float f) {  // RNE f32 -> bf16 (manual; cold paths)
    union { float f; unsigned u; } c; c.f = f;
    unsigned r = 0x7FFFu + ((c.u >> 16) & 1u);
    return (u16)((c.u + r) >> 16);
}
__device__ __forceinline__ u16 f2bf_hw(float f) {  // compiler fptrunc (RNE, packs to v_cvt_pk_bf16_f32)
    union { __hip_bfloat16 b; u16 u; } c; c.b = __float2bfloat16(f); return c.u;
}

#define B_   4
#define N_   2048
#define INC  256
#define H_   8
#define ROWS 8192

// canonical (bf16) segment offsets within cvt, u16 units. Weights stored TRANSPOSED: Bt[n][k].
#define SEG_X     0
#define SEG_LN1G  2097152
#define SEG_LN1B  2097408
#define SEG_WQKV  2097664
#define SEG_BQKV  2753024
#define SEG_WM    2755584
#define SEG_BM    3279872
#define SEG_LN2G  3280128
#define SEG_LN2B  3280384
#define SEG_W1    3280640
#define SEG_B1    3542784
#define SEG_W2    3543808
#define SEG_B2    3805952
#define SEG_TOT   3806208

// ---------------- self-sniff helper: detect fp32 vs bf16 inputs from x[0..1023] ----------
__device__ __forceinline__ int sniff_flag(const void* x0, int t, int* sh) {
    if (t == 0) *sh = 0;
    __syncthreads();
    int bad = 0;
    #pragma unroll
    for (int k2 = 0; k2 < 4; ++k2) {
        float v = bf2f(((const u16*)x0)[t * 4 + k2]);
        if (!(fabsf(v) < 1e10f)) bad = 1;
    }
    if (bad) atomicOr(sh, 1);
    __syncthreads();
    return *sh;   // 1 => fp32 inputs, 0 => bf16
}

// ---------------- unified prep: x+LN1, biases, mkz zero, weight transposes --------------
// blocks 0..8191: one x row each (convert + fused LN1 -> y).
// blocks 8192..8209: bias segments (block 8192 also zeroes mkz).
// blocks 8210..8625: 64x64 LDS-tiled weight transpose+convert (coalesced both sides).
__global__ __launch_bounds__(256) void prep_k(
    const void* p0, const void* p1, const void* p2, const void* p3, const void* p4,
    const void* p5, const void* p6, const void* p7, const void* p8, const void* p9,
    const void* p10, const void* p11, const void* p12,
    u16* __restrict__ dst, u16* __restrict__ y, int* __restrict__ mkz)
{
    const int t = threadIdx.x;
    const int blk = blockIdx.x;
    __shared__ int sflag;
    const int flag = sniff_flag(p0, t, &sflag);

    if (blk < 8192) {         // x row: convert + fused LN1
        const int i = blk * 256 + t;
        float v = flag ? ((const float*)p0)[i] : bf2f(((const u16*)p0)[i]);
        dst[i] = f2bf_hw(v);
        float s = v, s2 = v * v;
        #pragma unroll
        for (int d = 1; d < 64; d <<= 1) {
            s  += __shfl_xor(s,  d, 64);
            s2 += __shfl_xor(s2, d, 64);
        }
        __shared__ float rs[8];
        int w = t >> 6;
        if ((t & 63) == 0) { rs[w] = s; rs[4 + w] = s2; }
        __syncthreads();
        s  = rs[0] + rs[1] + rs[2] + rs[3];
        s2 = rs[4] + rs[5] + rs[6] + rs[7];
        float mean = s * (1.0f / INC);
        float var  = s2 * (1.0f / INC) - mean * mean;
        float inv  = rsqrtf(var + 1e-5f);
        float g  = flag ? ((const float*)p1)[t] : bf2f(((const u16*)p1)[t]);
        float bb = flag ? ((const float*)p2)[t] : bf2f(((const u16*)p2)[t]);
        y[i] = f2bf_hw((v - mean) * inv * g + bb);
        return;
    }

    if (blk < 8210) {         // bias segments
        if (blk == 8192 && t < 32) mkz[t] = 0;
        const int elem = (blk - 8192) * 256 + t;   // 0..4607 over concatenated bias segs
        const void* p; int j; size_t doff;
        if      (elem < 2560) { p = p4;  j = elem;        doff = SEG_BQKV + j; }
        else if (elem < 2816) { p = p6;  j = elem - 2560; doff = SEG_BM   + j; }
        else if (elem < 3072) { p = p7;  j = elem - 2816; doff = SEG_LN2G + j; }
        else if (elem < 3328) { p = p8;  j = elem - 3072; doff = SEG_LN2B + j; }
        else if (elem < 4352) { p = p10; j = elem - 3328; doff = SEG_B1   + j; }
        else                  { p = p12; j = elem - 4352; doff = SEG_B2   + j; }
        dst[doff] = flag ? f2bf(((const float*)p)[j]) : ((const u16*)p)[j];
        return;
    }

    // weight transpose: Wqkv 160 tiles, Wm 128, W1 64, W2 64
    const int blk2 = blk - 8210;
    const void* W; int Kd, Nd, kt, nt; size_t seg;
    if (blk2 < 160)      { W = p3;  Kd = 256;  Nd = 2560; kt = blk2 / 40;  nt = blk2 % 40;  seg = SEG_WQKV; }
    else if (blk2 < 288) { int i2 = blk2 - 160; W = p5;  Kd = 2048; Nd = 256;  kt = i2 >> 2;  nt = i2 & 3;  seg = SEG_WM; }
    else if (blk2 < 352) { int i2 = blk2 - 288; W = p9;  Kd = 256;  Nd = 1024; kt = i2 >> 4;  nt = i2 & 15; seg = SEG_W1; }
    else                 { int i2 = blk2 - 352; W = p11; Kd = 1024; Nd = 256;  kt = i2 >> 2;  nt = i2 & 3;  seg = SEG_W2; }
    const int k0 = kt * 64, n0 = nt * 64;

    __shared__ u16 Tl[64][66];
    #pragma unroll
    for (int p = 0; p < 16; ++p) {
        int idx = t + p * 256;
        int r = idx >> 6, c = idx & 63;
        size_t si = (size_t)(k0 + r) * Nd + n0 + c;
        Tl[r][c] = flag ? f2bf(((const float*)W)[si]) : ((const u16*)W)[si];
    }
    __syncthreads();
    u16* dp = dst + seg;
    #pragma unroll
    for (int p = 0; p < 8; ++p) {
        int idx = t + p * 256;
        int rn = idx >> 5, ck = (idx & 31) * 2;
        ushort2 v; v.x = Tl[ck][rn]; v.y = Tl[ck + 1][rn];
        *(ushort2*)(dp + (size_t)(n0 + rn) * Kd + k0 + ck) = v;   // Wt[n][k] = W[k][n]
    }
}

// ---------------- LayerNorm (f32 input), one wave per row, 4 rows/block ----------------
template<bool BF16IN>
__global__ __launch_bounds__(256) void ln_k(const void* __restrict__ xp,
        const u16* __restrict__ g, const u16* __restrict__ b, u16* __restrict__ y)
{
    int row  = blockIdx.x * 4 + (threadIdx.x >> 6);
    int lane = threadIdx.x & 63;
    int c0   = lane * 4;
    float v[4];
    if (BF16IN) {
        ushort4 u = *(const ushort4*)((const u16*)xp + (size_t)row * INC + c0);
        v[0] = bf2f(u.x); v[1] = bf2f(u.y); v[2] = bf2f(u.z); v[3] = bf2f(u.w);
    } else {
        float4 f = *(const float4*)((const float*)xp + (size_t)row * INC + c0);
        v[0] = f.x; v[1] = f.y; v[2] = f.z; v[3] = f.w;
    }
    float s = v[0] + v[1] + v[2] + v[3];
    float s2 = v[0]*v[0] + v[1]*v[1] + v[2]*v[2] + v[3]*v[3];
    #pragma unroll
    for (int d = 1; d < 64; d <<= 1) {
        s  += __shfl_xor(s,  d, 64);
        s2 += __shfl_xor(s2, d, 64);
    }
    float mean = s * (1.0f / INC);
    float var  = s2 * (1.0f / INC) - mean * mean;
    float inv  = rsqrtf(var + 1e-5f);
    ushort4 gv = *(const ushort4*)(g + c0);
    ushort4 bv = *(const ushort4*)(b + c0);
    ushort4 o;
    o.x = f2bf_hw((v[0] - mean) * inv * bf2f(gv.x) + bf2f(bv.x));
    o.y = f2bf_hw((v[1] - mean) * inv * bf2f(gv.y) + bf2f(bv.y));
    o.z = f2bf_hw((v[2] - mean) * inv * bf2f(gv.z) + bf2f(bv.z));
    o.w = f2bf_hw((v[3] - mean) * inv * bf2f(gv.w) + bf2f(bv.w));
    *(ushort4*)(y + (size_t)row * INC + c0) = o;
}

enum { EP_QKV = 0, EP_MERGE = 1, EP_GELU = 2, EP_FFN2 = 3 };

// ---------------- big-tile GEMM (QKV / GELU): wave 64x64, block 256x64, 2:1 MFMA:load ----
// QKV K-epilogue also computes per-head max key L2-norm^2 via shuffle-reduce + atomicMax.
// GELU epilogue LDS-retiled -> coalesced 128B row-run stores.
template<int MODE>
__global__ __launch_bounds__(256) void gemm_big(
    const u16* __restrict__ A, const u16* __restrict__ Bt,
    const u16* __restrict__ bias, void* __restrict__ outp,
    u16* __restrict__ qh, u16* __restrict__ kh, u16* __restrict__ vh,
    int* __restrict__ mkz, int N, int K)
{
    const int t = threadIdx.x;
    const int w = t >> 6, lane = t & 63;
    const int l15 = lane & 15, quad = lane >> 4;
    const int col0 = blockIdx.x * 64;
    const int row0 = blockIdx.y * 256;
    const int mrow = row0 + w * 64;

    __shared__ u16 Tsu[256 * 72];   // GELU: [256][72]; V path: [64][268] (both fit, 36.9KB)

    const u16* Ap = A  + (size_t)(mrow + l15) * K + quad * 8;
    const u16* Bp = Bt + (size_t)(col0 + l15) * K + quad * 8;

    f4_t acc[4][4];
    #pragma unroll
    for (int mi = 0; mi < 4; ++mi)
        #pragma unroll
        for (int ni = 0; ni < 4; ++ni)
            acc[mi][ni] = (f4_t){0.f, 0.f, 0.f, 0.f};

    for (int k0 = 0; k0 < K; k0 += 32) {
        bf8_t a[4], bb[4];
        #pragma unroll
        for (int mi = 0; mi < 4; ++mi)
            a[mi] = *(const bf8_t*)(Ap + (size_t)mi * 16 * K + k0);
        #pragma unroll
        for (int ni = 0; ni < 4; ++ni)
            bb[ni] = *(const bf8_t*)(Bp + (size_t)ni * 16 * K + k0);
        #pragma unroll
        for (int ni = 0; ni < 4; ++ni)
            #pragma unroll
            for (int mi = 0; mi < 4; ++mi)
                acc[mi][ni] = __builtin_amdgcn_mfma_f32_16x16x32_bf16(
                    a[mi], bb[ni], acc[mi][ni], 0, 0, 0);
    }

    if (MODE == EP_QKV) {
        if (col0 >= 512) {
            // V: transpose 256 tokens x 64 chans through LDS -> vh tiled [bh][tok/16][vc256][tok%16]
            u16 (*Ts)[268] = (u16(*)[268])Tsu;
            #pragma unroll
            for (int mi = 0; mi < 4; ++mi)
                #pragma unroll
                for (int ni = 0; ni < 4; ++ni) {
                    float bz = bf2f(bias[col0 + ni * 16 + l15]);
                    #pragma unroll
                    for (int r = 0; r < 4; ++r)
                        Ts[ni * 16 + l15][w * 64 + mi * 16 + quad * 4 + r] =
                            f2bf_hw(acc[mi][ni][r] + bz);
                }
            __syncthreads();
            int vcg = col0 - 512;
            int hh  = vcg >> 8;
            int bb2 = row0 >> 11, nb = row0 & 2047;
            int bhh = bb2 * 8 + hh;
            int tok4 = t & 3, cl = (t >> 2) & 63;
            int vc = (vcg & 255) + cl;
            // each kb-iteration: 256 threads store one fully-contiguous 2KB tile
            #pragma unroll
            for (int kb = 0; kb < 16; ++kb) {
                u16* dp = vh + (((size_t)bhh * 128 + ((nb >> 4) + kb)) * 256 + vc) * 16 + tok4 * 4;
                *(ushort4*)dp = *(const ushort4*)&Ts[cl][kb * 16 + tok4 * 4];
            }
        } else if (col0 < 256) {   // Q cols
            #pragma unroll
            for (int mi = 0; mi < 4; ++mi)
                #pragma unroll
                for (int r = 0; r < 4; ++r) {
                    int rg = mrow + mi * 16 + quad * 4 + r;
                    int bb2 = rg >> 11, n = rg & 2047;
                    #pragma unroll
                    for (int ni = 0; ni < 4; ++ni) {
                        int col = col0 + ni * 16 + l15;
                        float v = acc[mi][ni][r] + bf2f(bias[col]);
                        qh[(((size_t)(bb2 * 8 + (col >> 5))) * 2048 + n) * 32 + (col & 31)] = f2bf_hw(v);
                    }
                }
        } else {                   // K cols: store tiled + fused per-head max norm^2
            const int hA  = (col0 - 256) >> 5;       // block covers heads hA, hA+1
            const int bb2 = row0 >> 11;
            float mxA = 0.f, mxB = 0.f;
            #pragma unroll
            for (int mi = 0; mi < 4; ++mi)
                #pragma unroll
                for (int r = 0; r < 4; ++r) {
                    int rg = mrow + mi * 16 + quad * 4 + r;
                    int n = rg & 2047;
                    float vv[4];
                    #pragma unroll
                    for (int ni = 0; ni < 4; ++ni) {
                        int col = col0 + ni * 16 + l15;
                        float v = acc[mi][ni][r] + bf2f(bias[col]);
                        vv[ni] = v;
                        int c2 = col - 256;
                        int hd = c2 >> 5, ch = c2 & 31;
                        // K tiled: [bh][n/32][ch/16][n%32][ch%16]
                        kh[(((size_t)(bb2 * 8 + hd) * 64 + (n >> 5)) * 2 + (ch >> 4)) * 512
                           + (n & 31) * 16 + (ch & 15)] = f2bf_hw(v);
                    }
                    float sA = vv[0] * vv[0] + vv[1] * vv[1];
                    float sB = vv[2] * vv[2] + vv[3] * vv[3];
                    #pragma unroll
                    for (int d = 1; d < 16; d <<= 1) {
                        sA += __shfl_xor(sA, d, 64);
                        sB += __shfl_xor(sB, d, 64);
                    }
                    mxA = fmaxf(mxA, sA);
                    mxB = fmaxf(mxB, sB);
                }
            if ((lane & 15) == 0) {
                atomicMax(mkz + bb2 * 8 + hA,     __float_as_int(mxA));
                atomicMax(mkz + bb2 * 8 + hA + 1, __float_as_int(mxB));
            }
        }
    } else {   // EP_GELU: exact gelu -> LDS retile -> coalesced bf16 stores
        u16 (*Ts2)[72] = (u16(*)[72])Tsu;
        float bz[4];
        #pragma unroll
        for (int ni = 0; ni < 4; ++ni) bz[ni] = bf2f(bias[col0 + ni * 16 + l15]);
        #pragma unroll
        for (int mi = 0; mi < 4; ++mi)
            #pragma unroll
            for (int ni = 0; ni < 4; ++ni)
                #pragma unroll
                for (int r = 0; r < 4; ++r) {
                    float v = acc[mi][ni][r] + bz[ni];
                    v = 0.5f * v * (1.0f + erff(v * 0.70710678118654752f));
                    Ts2[w * 64 + mi * 16 + quad * 4 + r][ni * 16 + l15] = f2bf_hw(v);
                }
        __syncthreads();
        const int rl0 = t >> 3, c8 = (t & 7) * 8;
        #pragma unroll
        for (int p = 0; p < 8; ++p) {
            int rl = rl0 + p * 32;
            *(bf8_t*)((u16*)outp + (size_t)(row0 + rl) * N + col0 + c8) =
                *(const bf8_t*)&Ts2[rl][c8];
        }
    }
}

// ---------------- MFMA GEMM (MERGE / FFN2): block 128x64; LDS-retiled epilogue ----------
template<int MODE>
__global__ __launch_bounds__(256) void gemm_mfma(
    const u16* __restrict__ A, const u16* __restrict__ Bt,
    const u16* __restrict__ bias, const void* __restrict__ res,
    void* __restrict__ outp, int N, int K)
{
    const int t = threadIdx.x;
    const int w = t >> 6, lane = t & 63;
    const int l15 = lane & 15, quad = lane >> 4;
    const int col0 = blockIdx.x * 64;
    const int row0 = blockIdx.y * 128;
    const int mrow = row0 + w * 32;

    __shared__ float Tf[128][68];   // 34.8 KB; stride 68 f32 keeps float4 16B-aligned

    const u16* Ap = A  + (size_t)(mrow + l15) * K + quad * 8;
    const u16* Bp = Bt + (size_t)(col0 + l15) * K + quad * 8;

    f4_t acc[2][4];
    #pragma unroll
    for (int mi = 0; mi < 2; ++mi)
        #pragma unroll
        for (int ni = 0; ni < 4; ++ni)
            acc[mi][ni] = (f4_t){0.f, 0.f, 0.f, 0.f};

    for (int k0 = 0; k0 < K; k0 += 64) {
        bf8_t a[2][2], bb[4][2];
        #pragma unroll
        for (int kc = 0; kc < 2; ++kc) {
            #pragma unroll
            for (int mi = 0; mi < 2; ++mi)
                a[mi][kc] = *(const bf8_t*)(Ap + (size_t)mi * 16 * K + k0 + kc * 32);
            #pragma unroll
            for (int ni = 0; ni < 4; ++ni)
                bb[ni][kc] = *(const bf8_t*)(Bp + (size_t)ni * 16 * K + k0 + kc * 32);
        }
        #pragma unroll
        for (int kc = 0; kc < 2; ++kc)
            #pragma unroll
            for (int ni = 0; ni < 4; ++ni)
                #pragma unroll
                for (int mi = 0; mi < 2; ++mi)
                    acc[mi][ni] = __builtin_amdgcn_mfma_f32_16x16x32_bf16(
                        a[mi][kc], bb[ni][kc], acc[mi][ni], 0, 0, 0);
    }

    float bz[4];
    #pragma unroll
    for (int ni = 0; ni < 4; ++ni) bz[ni] = bf2f(bias[col0 + ni * 16 + l15]);
    #pragma unroll
    for (int mi = 0; mi < 2; ++mi)
        #pragma unroll
        for (int ni = 0; ni < 4; ++ni)
            #pragma unroll
            for (int r = 0; r < 4; ++r)
                Tf[w * 32 + mi * 16 + quad * 4 + r][ni * 16 + l15] = acc[mi][ni][r] + bz[ni];
    __syncthreads();

    const int rl0 = t >> 4, c4 = (t & 15) * 4;
    #pragma unroll
    for (int p = 0; p < 8; ++p) {
        int rl = rl0 + p * 16;
        float4 v = *(const float4*)&Tf[rl][c4];
        size_t base = (size_t)(row0 + rl) * N + col0 + c4;
        if (MODE == EP_MERGE) {          // + x (bf16 residual) -> f32 x2
            ushort4 rv = *(const ushort4*)((const u16*)res + base);
            v.x += bf2f(rv.x); v.y += bf2f(rv.y); v.z += bf2f(rv.z); v.w += bf2f(rv.w);
        } else {                          // EP_FFN2: + x2 (f32 residual) -> fp32 d_out
            float4 rv = *(const float4*)((const float*)res + base);
            v.x += rv.x; v.y += rv.y; v.z += rv.z; v.w += rv.w;
        }
        *(float4*)((float*)outp + base) = v;
    }
}

// ---------------- MFMA flash attention, 32x32x16, software-pipelined (R8-proven) ----------
__global__ __launch_bounds__(256) void attn_k(
    const u16* __restrict__ qh, const u16* __restrict__ kh,
    const u16* __restrict__ vhT, const float* __restrict__ mk2,
    u16* __restrict__ ao)
{
    const int t = threadIdx.x;
    const int w = t >> 6, lane = t & 63;
    const int l31 = lane & 31, hi = lane >> 5;
    const int id = blockIdx.x;
    const int qt = (id >> 3) & 31;
    const int bh = (id >> 8) * 8 + (id & 7);   // id%8 = XCD affinity per (b,h)
    const int b  = bh >> 3, h = bh & 7;
    const int n0 = qt * 64;
    const float SCALE = 0.17677669529663687f;  // 1/sqrt(32)
    const int sw = (l31 & 7) << 4;             // LDS XOR swizzle (byte bits 4-6)

    __shared__ __align__(16) u16 Pb[2][64][128];  // [buf][q][key], stride 256B, XOR-swizzled
    __shared__ float lds_l[4][64];
    __shared__ float lds_t[64];

    // Q fragments: qf[m][ks] = Q[n0+m*32+l31][ks*16 + hi*8 .. +8]  (B operand of QK)
    bf8_t qf[2][2];
    #pragma unroll
    for (int m = 0; m < 2; ++m)
        #pragma unroll
        for (int ks = 0; ks < 2; ++ks)
            qf[m][ks] = *(const bf8_t*)(qh + ((size_t)bh * 2048 + n0 + m * 32 + l31) * 32
                                        + ks * 16 + hi * 8);

    float mrow[2];
    #pragma unroll
    for (int m = 0; m < 2; ++m) {
        float q2 = 0.f;
        #pragma unroll
        for (int ks = 0; ks < 2; ++ks)
            #pragma unroll
            for (int i = 0; i < 8; ++i) {
                float qv = bf2f((u16)qf[m][ks][i]); q2 += qv * qv;
            }
        q2 += __shfl_xor(q2, 32, 64);
        mrow[m] = SCALE * sqrtf(q2 * mk2[bh]);
    }

    fx16 acc[2][2];
    #pragma unroll
    for (int a1 = 0; a1 < 2; ++a1)
        #pragma unroll
        for (int a2 = 0; a2 < 2; ++a2)
            #pragma unroll
            for (int e = 0; e < 16; ++e) acc[a1][a2][e] = 0.f;
    float lsum[2] = {0.f, 0.f};

    fx16 z16;
    #pragma unroll
    for (int e = 0; e < 16; ++e) z16[e] = 0.f;

    // exp + pack + P-write for one (m, g) group of a score tile
    auto finish = [&](const fx16& s, int m, int g, char* base) {
        float p0 = __expf(fmaf(s[4 * g + 0], SCALE, -mrow[m]));
        float p1 = __expf(fmaf(s[4 * g + 1], SCALE, -mrow[m]));
        float p2 = __expf(fmaf(s[4 * g + 2], SCALE, -mrow[m]));
        float p3 = __expf(fmaf(s[4 * g + 3], SCALE, -mrow[m]));
        lsum[m] += (p0 + p1) + (p2 + p3);
        ushort4 pk;
        pk.x = f2bf_hw(p0); pk.y = f2bf_hw(p1); pk.z = f2bf_hw(p2); pk.w = f2bf_hw(p3);
        *(ushort4*)(base + (m * 32 + l31) * 256 + ((w * 64 + 16 * g + 8 * hi) ^ sw)) = pk;
    };

    // K frags for chunk c: 32 keys starting at c*128 + w*32, both 16-chan halves
    bf8_t kA0, kA1;
    auto ldK = [&](int c) {
        const u16* kp = kh + ((size_t)bh * 64 + c * 4 + w) * 1024 + l31 * 16 + hi * 8;
        kA0 = *(const bf8_t*)kp;
        kA1 = *(const bf8_t*)(kp + 512);
    };

    // prologue: chunk 0 scores -> Pb[0]; preload K(1)
    {
        ldK(0);
        fx16 sA = __builtin_amdgcn_mfma_f32_32x32x16_bf16(kA0, qf[0][0], z16, 0, 0, 0);
        sA = __builtin_amdgcn_mfma_f32_32x32x16_bf16(kA1, qf[0][1], sA, 0, 0, 0);
        fx16 sB = __builtin_amdgcn_mfma_f32_32x32x16_bf16(kA0, qf[1][0], z16, 0, 0, 0);
        sB = __builtin_amdgcn_mfma_f32_32x32x16_bf16(kA1, qf[1][1], sB, 0, 0, 0);
        ldK(1);
        char* base0 = (char*)&Pb[0][0][0];
        #pragma unroll
        for (int g = 0; g < 4; ++g) finish(sA, 0, g, base0);
        #pragma unroll
        for (int g = 0; g < 4; ++g) finish(sB, 1, g, base0);
    }

    // V pipeline: 1-deep register prefetch, continuous across chunk boundaries.
    const u16* vpb = vhT + (((size_t)bh * 128) * 256 + w * 64 + l31) * 16 + hi * 8;
    bf8_t vb0 = *(const bf8_t*)vpb;
    bf8_t vb1 = *(const bf8_t*)(vpb + 512);

    int buf = 0;
    for (int c = 0; c < 16; ++c, buf ^= 1) {
        __syncthreads();
        const bool qn = (c < 15);
        fx16 sA, sB;
        if (qn) {   // scores for chunk c+1, q-tile m=0 (kA holds K(c+1))
            sA = __builtin_amdgcn_mfma_f32_32x32x16_bf16(kA0, qf[0][0], z16, 0, 0, 0);
            sA = __builtin_amdgcn_mfma_f32_32x32x16_bf16(kA1, qf[0][1], sA, 0, 0, 0);
        }
        const char* pb = (const char*)&Pb[buf][0][0];
        char* wr = (char*)&Pb[buf ^ 1][0][0];
        const u16* vp = vpb + (size_t)c * 32768;
        #pragma unroll
        for (int ks = 0; ks < 8; ++ks) {
            bf8_t nv0 = *(const bf8_t*)(vp + (ks + 1) * 4096);
            bf8_t nv1 = *(const bf8_t*)(vp + (ks + 1) * 4096 + 512);
            bf8_t pa0 = *(const bf8_t*)(pb + l31 * 256        + ((ks * 32 + hi * 16) ^ sw));
            bf8_t pa1 = *(const bf8_t*)(pb + (32 + l31) * 256 + ((ks * 32 + hi * 16) ^ sw));
            __builtin_amdgcn_s_setprio(1);
            acc[0][0] = __builtin_amdgcn_mfma_f32_32x32x16_bf16(pa0, vb0, acc[0][0], 0, 0, 0);
            acc[0][1] = __builtin_amdgcn_mfma_f32_32x32x16_bf16(pa0, vb1, acc[0][1], 0, 0, 0);
            acc[1][0] = __builtin_amdgcn_mfma_f32_32x32x16_bf16(pa1, vb0, acc[1][0], 0, 0, 0);
            acc[1][1] = __builtin_amdgcn_mfma_f32_32x32x16_bf16(pa1, vb1, acc[1][1], 0, 0, 0);
            __builtin_amdgcn_s_setprio(0);
            if (qn) {
                if (ks < 4) {
                    finish(sA, 0, ks, wr);
                    if (ks == 3) {   // sA consumed: compute m=1 scores, then recycle kA
                        sB = __builtin_amdgcn_mfma_f32_32x32x16_bf16(kA0, qf[1][0], z16, 0, 0, 0);
                        sB = __builtin_amdgcn_mfma_f32_32x32x16_bf16(kA1, qf[1][1], sB, 0, 0, 0);
                        if (c < 14) ldK(c + 2);
                    }
                } else {
                    finish(sB, 1, ks - 4, wr);
                }
            }
            vb0 = nv0; vb1 = nv1;
        }
    }

    // cross-wave lsum reduction
    #pragma unroll
    for (int m = 0; m < 2; ++m) {
        lsum[m] += __shfl_xor(lsum[m], 32, 64);
        if (hi == 0) lds_l[w][m * 32 + l31] = lsum[m];
    }
    __syncthreads();
    if (t < 64) lds_t[t] = lds_l[0][t] + lds_l[1][t] + lds_l[2][t] + lds_l[3][t];
    __syncthreads();

    #pragma unroll
    for (int mt = 0; mt < 2; ++mt)
        #pragma unroll
        for (int g = 0; g < 4; ++g) {
            f4_t lv = *(const f4_t*)&lds_t[mt * 32 + 8 * g + 4 * hi];
            #pragma unroll
            for (int j = 0; j < 4; ++j) {
                float inv = 1.0f / lv[j];
                int q = mt * 32 + 8 * g + 4 * hi + j;
                size_t rowbase = ((size_t)(b * 2048 + n0 + q)) * 2048 + h * 256 + w * 64;
                #pragma unroll
                for (int nt = 0; nt < 2; ++nt)
                    ao[rowbase + nt * 32 + l31] = f2bf_hw(acc[mt][nt][g * 4 + j] * inv);
            }
        }
}

extern "C" void kernel_launch(void* const* d_in, const int* in_sizes, int n_in,
                              void* d_out, int out_size, void* d_ws, size_t ws_size,
                              hipStream_t stream)
{
    u16* wsu = (u16*)d_ws;
    float* mk = (float*)(wsu + 64);              // 32 f32 (max key norm^2, int-atomics)

    // workspace layout (u16 units), ~95.7 MB (known-safe)
    const size_t CVT0 = 128;
    const size_t Y0   = CVT0 + SEG_TOT;          // y bf16 [8192,256]
    const size_t QH0  = Y0  + 2097152;
    const size_t KH0  = QH0 + 2097152;           // K tiled [bh][64][2][32][16]
    const size_t VT0  = KH0 + 2097152;           // V tiled [bh][128][256][16]
    const size_t AO0  = VT0 + 16777216;          // ao bf16 [8192][2048]
    const size_t X20  = AO0 + 16777216;          // x2 f32 [8192,256]
    // hbb bf16 [8192,1024] aliases AO0 (ao dead after merge GEMM)

    u16* cvt = wsu + CVT0;
    u16* y   = wsu + Y0;
    u16* qh  = wsu + QH0;
    u16* kh  = wsu + KH0;
    u16* vhT = wsu + VT0;
    u16* ao  = wsu + AO0;
    float* x2 = (float*)(wsu + X20);
    u16* hbb  = wsu + AO0;

    const u16* xc   = cvt + SEG_X;
    const u16* Wqkv = cvt + SEG_WQKV;   // transposed [2560][256]
    const u16* bqkv = cvt + SEG_BQKV;
    const u16* Wm   = cvt + SEG_WM;     // transposed [256][2048]
    const u16* bm   = cvt + SEG_BM;
    const u16* ln2g = cvt + SEG_LN2G;
    const u16* ln2b = cvt + SEG_LN2B;
    const u16* W1   = cvt + SEG_W1;     // transposed [1024][256]
    const u16* b1   = cvt + SEG_B1;
    const u16* W2   = cvt + SEG_W2;     // transposed [256][1024]
    const u16* b2   = cvt + SEG_B2;

    // unified prep: x+LN1 (8192) + biases/mkz (18) + weight transposes (416)
    prep_k<<<8626, 256, 0, stream>>>(
        d_in[0], d_in[1], d_in[2], d_in[3], d_in[4], d_in[5], d_in[6],
        d_in[7], d_in[8], d_in[9], d_in[10], d_in[11], d_in[12],
        cvt, y, (int*)mk);

    // ===== R12 MEASUREMENT ROUND: each GEMM dispatched twice, idempotently =====
    // (same inputs -> same outputs; atomicMax re-applies identical values; no reader
    //  between original and dup. dTotal vs R11's 331.2us = warm-cache sum of the 4
    //  GEMM durations + 4 gaps -> localizes the invisible ~235us non-attn residue.)
    gemm_big<EP_QKV><<<dim3(2560 / 64, ROWS / 256), 256, 0, stream>>>(
        y, Wqkv, bqkv, nullptr, qh, kh, vhT, (int*)mk, 2560, 256);
    gemm_big<EP_QKV><<<dim3(2560 / 64, ROWS / 256), 256, 0, stream>>>(
        y, Wqkv, bqkv, nullptr, qh, kh, vhT, (int*)mk, 2560, 256);   // dup

    attn_k<<<1024, 256, 0, stream>>>(qh, kh, vhT, mk, ao);

    gemm_mfma<EP_MERGE><<<dim3(256 / 64, ROWS / 128), 256, 0, stream>>>(
        ao, Wm, bm, xc, x2, 256, 2048);
    gemm_mfma<EP_MERGE><<<dim3(256 / 64, ROWS / 128), 256, 0, stream>>>(
        ao, Wm, bm, xc, x2, 256, 2048);                              // dup

    ln_k<false><<<ROWS / 4, 256, 0, stream>>>(x2, ln2g, ln2b, y);

    gemm_big<EP_GELU><<<dim3(1024 / 64, ROWS / 256), 256, 0, stream>>>(
        y, W1, b1, hbb, nullptr, nullptr, nullptr, nullptr, 1024, 256);
    gemm_big<EP_GELU><<<dim3(1024 / 64, ROWS / 256), 256, 0, stream>>>(
        y, W1, b1, hbb, nullptr, nullptr, nullptr, nullptr, 1024, 256);  // dup

    gemm_mfma<EP_FFN2><<<dim3(256 / 64, ROWS / 128), 256, 0, stream>>>(
        hbb, W2, b2, x2, d_out, 256, 1024);
    gemm_mfma<EP_FFN2><<<dim3(256 / 64, ROWS / 128), 256, 0, stream>>>(
        hbb, W2, b2, x2, d_out, 256, 1024);                          // dup
}

// Round 13
// 294.795 us; speedup vs baseline: 1.6396x; 1.6396x over previous
//
#include <hip/hip_runtime.h>
#include <hip/hip_bf16.h>

typedef unsigned short u16;
typedef __attribute__((ext_vector_type(8))) short bf8_t;   // 8 bf16 (4 VGPR) MFMA A/B frag
typedef __attribute__((ext_vector_type(4))) float f4_t;    // MFMA C/D frag (16x16)
typedef __attribute__((ext_vector_type(16))) float fx16;   // MFMA C/D frag (32x32)

__device__ __forceinline__ float bf2f(u16 v) {
    union { unsigned u; float f; } c; c.u = ((unsigned)v) << 16; return c.f;
}
__device__ __forceinline__ u16 f2bf(float f) {  // RNE f32 -> bf16 (manual; cold paths)
    union { float f; unsigned u; } c; c.f = f;
    unsigned r = 0x7FFFu + ((c.u >> 16) & 1u);
    return (u16)((c.u + r) >> 16);
}
__device__ __forceinline__ u16 f2bf_hw(float f) {  // compiler fptrunc (RNE, packs to v_cvt_pk_bf16_f32)
    union { __hip_bfloat16 b; u16 u; } c; c.b = __float2bfloat16(f); return c.u;
}

// async global->LDS, 16B per lane. LDS dest is wave-uniform base + lane*16 (linear);
// global src is per-lane. Source chunk is pre-swizzled by caller (rule 21).
typedef __attribute__((address_space(3))) unsigned as3_u32;
typedef __attribute__((address_space(1))) const unsigned as1_u32;
__device__ __forceinline__ void gl16(const u16* g, u16* l) {
    __builtin_amdgcn_global_load_lds((as1_u32*)(const void*)g, (as3_u32*)(void*)l, 16, 0, 0);
}

#define B_   4
#define N_   2048
#define INC  256
#define H_   8
#define ROWS 8192

// canonical (bf16) segment offsets within cvt, u16 units. Weights stored TRANSPOSED: Bt[n][k].
#define SEG_X     0
#define SEG_LN1G  2097152
#define SEG_LN1B  2097408
#define SEG_WQKV  2097664
#define SEG_BQKV  2753024
#define SEG_WM    2755584
#define SEG_BM    3279872
#define SEG_LN2G  3280128
#define SEG_LN2B  3280384
#define SEG_W1    3280640
#define SEG_B1    3542784
#define SEG_W2    3543808
#define SEG_B2    3805952
#define SEG_TOT   3806208

// ---------------- self-sniff helper: detect fp32 vs bf16 inputs from x[0..1023] ----------
__device__ __forceinline__ int sniff_flag(const void* x0, int t, int* sh) {
    if (t == 0) *sh = 0;
    __syncthreads();
    int bad = 0;
    #pragma unroll
    for (int k2 = 0; k2 < 4; ++k2) {
        float v = bf2f(((const u16*)x0)[t * 4 + k2]);
        if (!(fabsf(v) < 1e10f)) bad = 1;
    }
    if (bad) atomicOr(sh, 1);
    __syncthreads();
    return *sh;   // 1 => fp32 inputs, 0 => bf16
}

// ---------------- unified prep: x+LN1, biases, mkz zero, weight transposes --------------
__global__ __launch_bounds__(256) void prep_k(
    const void* p0, const void* p1, const void* p2, const void* p3, const void* p4,
    const void* p5, const void* p6, const void* p7, const void* p8, const void* p9,
    const void* p10, const void* p11, const void* p12,
    u16* __restrict__ dst, u16* __restrict__ y, int* __restrict__ mkz)
{
    const int t = threadIdx.x;
    const int blk = blockIdx.x;
    __shared__ int sflag;
    const int flag = sniff_flag(p0, t, &sflag);

    if (blk < 8192) {         // x row: convert + fused LN1
        const int i = blk * 256 + t;
        float v = flag ? ((const float*)p0)[i] : bf2f(((const u16*)p0)[i]);
        dst[i] = f2bf_hw(v);
        float s = v, s2 = v * v;
        #pragma unroll
        for (int d = 1; d < 64; d <<= 1) {
            s  += __shfl_xor(s,  d, 64);
            s2 += __shfl_xor(s2, d, 64);
        }
        __shared__ float rs[8];
        int w = t >> 6;
        if ((t & 63) == 0) { rs[w] = s; rs[4 + w] = s2; }
        __syncthreads();
        s  = rs[0] + rs[1] + rs[2] + rs[3];
        s2 = rs[4] + rs[5] + rs[6] + rs[7];
        float mean = s * (1.0f / INC);
        float var  = s2 * (1.0f / INC) - mean * mean;
        float inv  = rsqrtf(var + 1e-5f);
        float g  = flag ? ((const float*)p1)[t] : bf2f(((const u16*)p1)[t]);
        float bb = flag ? ((const float*)p2)[t] : bf2f(((const u16*)p2)[t]);
        y[i] = f2bf_hw((v - mean) * inv * g + bb);
        return;
    }

    if (blk < 8210) {         // bias segments
        if (blk == 8192 && t < 32) mkz[t] = 0;
        const int elem = (blk - 8192) * 256 + t;   // 0..4607 over concatenated bias segs
        const void* p; int j; size_t doff;
        if      (elem < 2560) { p = p4;  j = elem;        doff = SEG_BQKV + j; }
        else if (elem < 2816) { p = p6;  j = elem - 2560; doff = SEG_BM   + j; }
        else if (elem < 3072) { p = p7;  j = elem - 2816; doff = SEG_LN2G + j; }
        else if (elem < 3328) { p = p8;  j = elem - 3072; doff = SEG_LN2B + j; }
        else if (elem < 4352) { p = p10; j = elem - 3328; doff = SEG_B1   + j; }
        else                  { p = p12; j = elem - 4352; doff = SEG_B2   + j; }
        dst[doff] = flag ? f2bf(((const float*)p)[j]) : ((const u16*)p)[j];
        return;
    }

    // weight transpose: Wqkv 160 tiles, Wm 128, W1 64, W2 64
    const int blk2 = blk - 8210;
    const void* W; int Kd, Nd, kt, nt; size_t seg;
    if (blk2 < 160)      { W = p3;  Kd = 256;  Nd = 2560; kt = blk2 / 40;  nt = blk2 % 40;  seg = SEG_WQKV; }
    else if (blk2 < 288) { int i2 = blk2 - 160; W = p5;  Kd = 2048; Nd = 256;  kt = i2 >> 2;  nt = i2 & 3;  seg = SEG_WM; }
    else if (blk2 < 352) { int i2 = blk2 - 288; W = p9;  Kd = 256;  Nd = 1024; kt = i2 >> 4;  nt = i2 & 15; seg = SEG_W1; }
    else                 { int i2 = blk2 - 352; W = p11; Kd = 1024; Nd = 256;  kt = i2 >> 2;  nt = i2 & 3;  seg = SEG_W2; }
    const int k0 = kt * 64, n0 = nt * 64;

    __shared__ u16 Tl[64][66];
    #pragma unroll
    for (int p = 0; p < 16; ++p) {
        int idx = t + p * 256;
        int r = idx >> 6, c = idx & 63;
        size_t si = (size_t)(k0 + r) * Nd + n0 + c;
        Tl[r][c] = flag ? f2bf(((const float*)W)[si]) : ((const u16*)W)[si];
    }
    __syncthreads();
    u16* dp = dst + seg;
    #pragma unroll
    for (int p = 0; p < 8; ++p) {
        int idx = t + p * 256;
        int rn = idx >> 5, ck = (idx & 31) * 2;
        ushort2 v; v.x = Tl[ck][rn]; v.y = Tl[ck + 1][rn];
        *(ushort2*)(dp + (size_t)(n0 + rn) * Kd + k0 + ck) = v;   // Wt[n][k] = W[k][n]
    }
}

// ---------------- LayerNorm (f32 input), one wave per row, 4 rows/block ----------------
template<bool BF16IN>
__global__ __launch_bounds__(256) void ln_k(const void* __restrict__ xp,
        const u16* __restrict__ g, const u16* __restrict__ b, u16* __restrict__ y)
{
    int row  = blockIdx.x * 4 + (threadIdx.x >> 6);
    int lane = threadIdx.x & 63;
    int c0   = lane * 4;
    float v[4];
    if (BF16IN) {
        ushort4 u = *(const ushort4*)((const u16*)xp + (size_t)row * INC + c0);
        v[0] = bf2f(u.x); v[1] = bf2f(u.y); v[2] = bf2f(u.z); v[3] = bf2f(u.w);
    } else {
        float4 f = *(const float4*)((const float*)xp + (size_t)row * INC + c0);
        v[0] = f.x; v[1] = f.y; v[2] = f.z; v[3] = f.w;
    }
    float s = v[0] + v[1] + v[2] + v[3];
    float s2 = v[0]*v[0] + v[1]*v[1] + v[2]*v[2] + v[3]*v[3];
    #pragma unroll
    for (int d = 1; d < 64; d <<= 1) {
        s  += __shfl_xor(s,  d, 64);
        s2 += __shfl_xor(s2, d, 64);
    }
    float mean = s * (1.0f / INC);
    float var  = s2 * (1.0f / INC) - mean * mean;
    float inv  = rsqrtf(var + 1e-5f);
    ushort4 gv = *(const ushort4*)(g + c0);
    ushort4 bv = *(const ushort4*)(b + c0);
    ushort4 o;
    o.x = f2bf_hw((v[0] - mean) * inv * bf2f(gv.x) + bf2f(bv.x));
    o.y = f2bf_hw((v[1] - mean) * inv * bf2f(gv.y) + bf2f(bv.y));
    o.z = f2bf_hw((v[2] - mean) * inv * bf2f(gv.z) + bf2f(bv.z));
    o.w = f2bf_hw((v[3] - mean) * inv * bf2f(gv.w) + bf2f(bv.w));
    *(ushort4*)(y + (size_t)row * INC + c0) = o;
}

enum { EP_QKV = 0, EP_MERGE = 1, EP_GELU = 2, EP_FFN2 = 3 };

// ---------------- big-tile GEMM (QKV / GELU): block 256x64, BK=64, LDS-staged ----------
// R13: operands staged via global_load_lds (width 16, m97 structure). Source chunk
// pre-swizzled (ch ^= row&7) so ds_read_b128 fragment reads are conflict-free (<=2-way).
// MFMA order identical to R11 -> bit-identical results.
template<int MODE>
__global__ __launch_bounds__(256) void gemm_big(
    const u16* __restrict__ A, const u16* __restrict__ Bt,
    const u16* __restrict__ bias, void* __restrict__ outp,
    u16* __restrict__ qh, u16* __restrict__ kh, u16* __restrict__ vh,
    int* __restrict__ mkz, int N, int K)
{
    const int t = threadIdx.x;
    const int w = t >> 6, lane = t & 63;
    const int l15 = lane & 15, quad = lane >> 4;
    const int col0 = blockIdx.x * 64;
    const int row0 = blockIdx.y * 256;
    const int lr = lane >> 3;                  // row within 8-row staging group
    const int sc = ((lane & 7) ^ lr) * 8;      // pre-swizzled source chunk (u16 units)

    __shared__ __align__(16) u16 Sb[20480];    // 40KB: A[256][64] + B[64][64]; epilogue aliases
    u16* Al = Sb;
    u16* Bl = Sb + 16384;

    f4_t acc[4][4];
    #pragma unroll
    for (int mi = 0; mi < 4; ++mi)
        #pragma unroll
        for (int ni = 0; ni < 4; ++ni)
            acc[mi][ni] = (f4_t){0.f, 0.f, 0.f, 0.f};

    for (int k0 = 0; k0 < K; k0 += 64) {
        // stage A: wave w covers rows [w*64, w*64+64), 8 loads x 8 rows (1KB each, linear)
        #pragma unroll
        for (int i = 0; i < 8; ++i) {
            int r = w * 64 + i * 8;
            gl16(A + (size_t)(row0 + r + lr) * K + k0 + sc, Al + r * 64);
        }
        // stage B: wave w covers rows [w*16, w*16+16), 2 loads
        gl16(Bt + (size_t)(col0 + w * 16 + lr) * K + k0 + sc,     Bl + (w * 16) * 64);
        gl16(Bt + (size_t)(col0 + w * 16 + 8 + lr) * K + k0 + sc, Bl + (w * 16 + 8) * 64);
        __syncthreads();
        #pragma unroll
        for (int kc = 0; kc < 2; ++kc) {
            bf8_t a[4], bb[4];
            #pragma unroll
            for (int mi = 0; mi < 4; ++mi) {
                int row = w * 64 + mi * 16 + l15;
                a[mi] = *(const bf8_t*)(Al + row * 64 + ((kc * 4 + quad) ^ (row & 7)) * 8);
            }
            #pragma unroll
            for (int ni = 0; ni < 4; ++ni) {
                int row = ni * 16 + l15;
                bb[ni] = *(const bf8_t*)(Bl + row * 64 + ((kc * 4 + quad) ^ (row & 7)) * 8);
            }
            #pragma unroll
            for (int ni = 0; ni < 4; ++ni)
                #pragma unroll
                for (int mi = 0; mi < 4; ++mi)
                    acc[mi][ni] = __builtin_amdgcn_mfma_f32_16x16x32_bf16(
                        a[mi], bb[ni], acc[mi][ni], 0, 0, 0);
        }
        __syncthreads();   // also guards epilogue's reuse of Sb after last step
    }
    const int mrow = row0 + w * 64;

    if (MODE == EP_QKV) {
        if (col0 >= 512) {
            // V: transpose 256 tokens x 64 chans through LDS -> vh tiled [bh][tok/16][vc256][tok%16]
            u16 (*Ts)[268] = (u16(*)[268])Sb;
            #pragma unroll
            for (int mi = 0; mi < 4; ++mi)
                #pragma unroll
                for (int ni = 0; ni < 4; ++ni) {
                    float bz = bf2f(bias[col0 + ni * 16 + l15]);
                    #pragma unroll
                    for (int r = 0; r < 4; ++r)
                        Ts[ni * 16 + l15][w * 64 + mi * 16 + quad * 4 + r] =
                            f2bf_hw(acc[mi][ni][r] + bz);
                }
            __syncthreads();
            int vcg = col0 - 512;
            int hh  = vcg >> 8;
            int bb2 = row0 >> 11, nb = row0 & 2047;
            int bhh = bb2 * 8 + hh;
            int tok4 = t & 3, cl = (t >> 2) & 63;
            int vc = (vcg & 255) + cl;
            #pragma unroll
            for (int kb = 0; kb < 16; ++kb) {
                u16* dp = vh + (((size_t)bhh * 128 + ((nb >> 4) + kb)) * 256 + vc) * 16 + tok4 * 4;
                *(ushort4*)dp = *(const ushort4*)&Ts[cl][kb * 16 + tok4 * 4];
            }
        } else if (col0 < 256) {   // Q cols
            #pragma unroll
            for (int mi = 0; mi < 4; ++mi)
                #pragma unroll
                for (int r = 0; r < 4; ++r) {
                    int rg = mrow + mi * 16 + quad * 4 + r;
                    int bb2 = rg >> 11, n = rg & 2047;
                    #pragma unroll
                    for (int ni = 0; ni < 4; ++ni) {
                        int col = col0 + ni * 16 + l15;
                        float v = acc[mi][ni][r] + bf2f(bias[col]);
                        qh[(((size_t)(bb2 * 8 + (col >> 5))) * 2048 + n) * 32 + (col & 31)] = f2bf_hw(v);
                    }
                }
        } else {                   // K cols: store tiled + fused per-head max norm^2
            const int hA  = (col0 - 256) >> 5;
            const int bb2 = row0 >> 11;
            float mxA = 0.f, mxB = 0.f;
            #pragma unroll
            for (int mi = 0; mi < 4; ++mi)
                #pragma unroll
                for (int r = 0; r < 4; ++r) {
                    int rg = mrow + mi * 16 + quad * 4 + r;
                    int n = rg & 2047;
                    float vv[4];
                    #pragma unroll
                    for (int ni = 0; ni < 4; ++ni) {
                        int col = col0 + ni * 16 + l15;
                        float v = acc[mi][ni][r] + bf2f(bias[col]);
                        vv[ni] = v;
                        int c2 = col - 256;
                        int hd = c2 >> 5, ch = c2 & 31;
                        kh[(((size_t)(bb2 * 8 + hd) * 64 + (n >> 5)) * 2 + (ch >> 4)) * 512
                           + (n & 31) * 16 + (ch & 15)] = f2bf_hw(v);
                    }
                    float sA = vv[0] * vv[0] + vv[1] * vv[1];
                    float sB = vv[2] * vv[2] + vv[3] * vv[3];
                    #pragma unroll
                    for (int d = 1; d < 16; d <<= 1) {
                        sA += __shfl_xor(sA, d, 64);
                        sB += __shfl_xor(sB, d, 64);
                    }
                    mxA = fmaxf(mxA, sA);
                    mxB = fmaxf(mxB, sB);
                }
            if ((lane & 15) == 0) {
                atomicMax(mkz + bb2 * 8 + hA,     __float_as_int(mxA));
                atomicMax(mkz + bb2 * 8 + hA + 1, __float_as_int(mxB));
            }
        }
    } else {   // EP_GELU: exact gelu -> LDS retile -> coalesced bf16 stores
        u16 (*Ts2)[72] = (u16(*)[72])Sb;
        float bz[4];
        #pragma unroll
        for (int ni = 0; ni < 4; ++ni) bz[ni] = bf2f(bias[col0 + ni * 16 + l15]);
        #pragma unroll
        for (int mi = 0; mi < 4; ++mi)
            #pragma unroll
            for (int ni = 0; ni < 4; ++ni)
                #pragma unroll
                for (int r = 0; r < 4; ++r) {
                    float v = acc[mi][ni][r] + bz[ni];
                    v = 0.5f * v * (1.0f + erff(v * 0.70710678118654752f));
                    Ts2[w * 64 + mi * 16 + quad * 4 + r][ni * 16 + l15] = f2bf_hw(v);
                }
        __syncthreads();
        const int rl0 = t >> 3, c8 = (t & 7) * 8;
        #pragma unroll
        for (int p = 0; p < 8; ++p) {
            int rl = rl0 + p * 32;
            *(bf8_t*)((u16*)outp + (size_t)(row0 + rl) * N + col0 + c8) =
                *(const bf8_t*)&Ts2[rl][c8];
        }
    }
}

// ---------------- MFMA GEMM (MERGE / FFN2): block 128x64, BK=64, LDS-staged ------------
template<int MODE>
__global__ __launch_bounds__(256) void gemm_mfma(
    const u16* __restrict__ A, const u16* __restrict__ Bt,
    const u16* __restrict__ bias, const void* __restrict__ res,
    void* __restrict__ outp, int N, int K)
{
    const int t = threadIdx.x;
    const int w = t >> 6, lane = t & 63;
    const int l15 = lane & 15, quad = lane >> 4;
    const int col0 = blockIdx.x * 64;
    const int row0 = blockIdx.y * 128;
    const int lr = lane >> 3;
    const int sc = ((lane & 7) ^ lr) * 8;

    __shared__ __align__(16) float SBf[8704];   // 34.8KB: Tf[128][68]; staging aliases 24KB
    u16* Al = (u16*)SBf;                        // [128][64]
    u16* Bl = (u16*)SBf + 8192;                 // [64][64]
    float (*Tf)[68] = (float(*)[68])SBf;

    f4_t acc[2][4];
    #pragma unroll
    for (int mi = 0; mi < 2; ++mi)
        #pragma unroll
        for (int ni = 0; ni < 4; ++ni)
            acc[mi][ni] = (f4_t){0.f, 0.f, 0.f, 0.f};

    for (int k0 = 0; k0 < K; k0 += 64) {
        #pragma unroll
        for (int i = 0; i < 4; ++i) {
            int r = w * 32 + i * 8;
            gl16(A + (size_t)(row0 + r + lr) * K + k0 + sc, Al + r * 64);
        }
        gl16(Bt + (size_t)(col0 + w * 16 + lr) * K + k0 + sc,     Bl + (w * 16) * 64);
        gl16(Bt + (size_t)(col0 + w * 16 + 8 + lr) * K + k0 + sc, Bl + (w * 16 + 8) * 64);
        __syncthreads();
        #pragma unroll
        for (int kc = 0; kc < 2; ++kc) {
            bf8_t a[2], bb[4];
            #pragma unroll
            for (int mi = 0; mi < 2; ++mi) {
                int row = w * 32 + mi * 16 + l15;
                a[mi] = *(const bf8_t*)(Al + row * 64 + ((kc * 4 + quad) ^ (row & 7)) * 8);
            }
            #pragma unroll
            for (int ni = 0; ni < 4; ++ni) {
                int row = ni * 16 + l15;
                bb[ni] = *(const bf8_t*)(Bl + row * 64 + ((kc * 4 + quad) ^ (row & 7)) * 8);
            }
            #pragma unroll
            for (int ni = 0; ni < 4; ++ni)
                #pragma unroll
                for (int mi = 0; mi < 2; ++mi)
                    acc[mi][ni] = __builtin_amdgcn_mfma_f32_16x16x32_bf16(
                        a[mi], bb[ni], acc[mi][ni], 0, 0, 0);
        }
        __syncthreads();   // also guards Tf's reuse of the staging region
    }

    float bz[4];
    #pragma unroll
    for (int ni = 0; ni < 4; ++ni) bz[ni] = bf2f(bias[col0 + ni * 16 + l15]);
    #pragma unroll
    for (int mi = 0; mi < 2; ++mi)
        #pragma unroll
        for (int ni = 0; ni < 4; ++ni)
            #pragma unroll
            for (int r = 0; r < 4; ++r)
                Tf[w * 32 + mi * 16 + quad * 4 + r][ni * 16 + l15] = acc[mi][ni][r] + bz[ni];
    __syncthreads();

    const int rl0 = t >> 4, c4 = (t & 15) * 4;
    #pragma unroll
    for (int p = 0; p < 8; ++p) {
        int rl = rl0 + p * 16;
        float4 v = *(const float4*)&Tf[rl][c4];
        size_t base = (size_t)(row0 + rl) * N + col0 + c4;
        if (MODE == EP_MERGE) {          // + x (bf16 residual) -> f32 x2
            ushort4 rv = *(const ushort4*)((const u16*)res + base);
            v.x += bf2f(rv.x); v.y += bf2f(rv.y); v.z += bf2f(rv.z); v.w += bf2f(rv.w);
        } else {                          // EP_FFN2: + x2 (f32 residual) -> fp32 d_out
            float4 rv = *(const float4*)((const float*)res + base);
            v.x += rv.x; v.y += rv.y; v.z += rv.z; v.w += rv.w;
        }
        *(float4*)((float*)outp + base) = v;
    }
}

// ---------------- MFMA flash attention, 32x32x16, software-pipelined (R8-proven) ----------
__global__ __launch_bounds__(256) void attn_k(
    const u16* __restrict__ qh, const u16* __restrict__ kh,
    const u16* __restrict__ vhT, const float* __restrict__ mk2,
    u16* __restrict__ ao)
{
    const int t = threadIdx.x;
    const int w = t >> 6, lane = t & 63;
    const int l31 = lane & 31, hi = lane >> 5;
    const int id = blockIdx.x;
    const int qt = (id >> 3) & 31;
    const int bh = (id >> 8) * 8 + (id & 7);   // id%8 = XCD affinity per (b,h)
    const int b  = bh >> 3, h = bh & 7;
    const int n0 = qt * 64;
    const float SCALE = 0.17677669529663687f;  // 1/sqrt(32)
    const int sw = (l31 & 7) << 4;             // LDS XOR swizzle (byte bits 4-6)

    __shared__ __align__(16) u16 Pb[2][64][128];  // [buf][q][key], stride 256B, XOR-swizzled
    __shared__ float lds_l[4][64];
    __shared__ float lds_t[64];

    bf8_t qf[2][2];
    #pragma unroll
    for (int m = 0; m < 2; ++m)
        #pragma unroll
        for (int ks = 0; ks < 2; ++ks)
            qf[m][ks] = *(const bf8_t*)(qh + ((size_t)bh * 2048 + n0 + m * 32 + l31) * 32
                                        + ks * 16 + hi * 8);

    float mrow[2];
    #pragma unroll
    for (int m = 0; m < 2; ++m) {
        float q2 = 0.f;
        #pragma unroll
        for (int ks = 0; ks < 2; ++ks)
            #pragma unroll
            for (int i = 0; i < 8; ++i) {
                float qv = bf2f((u16)qf[m][ks][i]); q2 += qv * qv;
            }
        q2 += __shfl_xor(q2, 32, 64);
        mrow[m] = SCALE * sqrtf(q2 * mk2[bh]);
    }

    fx16 acc[2][2];
    #pragma unroll
    for (int a1 = 0; a1 < 2; ++a1)
        #pragma unroll
        for (int a2 = 0; a2 < 2; ++a2)
            #pragma unroll
            for (int e = 0; e < 16; ++e) acc[a1][a2][e] = 0.f;
    float lsum[2] = {0.f, 0.f};

    fx16 z16;
    #pragma unroll
    for (int e = 0; e < 16; ++e) z16[e] = 0.f;

    auto finish = [&](const fx16& s, int m, int g, char* base) {
        float p0 = __expf(fmaf(s[4 * g + 0], SCALE, -mrow[m]));
        float p1 = __expf(fmaf(s[4 * g + 1], SCALE, -mrow[m]));
        float p2 = __expf(fmaf(s[4 * g + 2], SCALE, -mrow[m]));
        float p3 = __expf(fmaf(s[4 * g + 3], SCALE, -mrow[m]));
        lsum[m] += (p0 + p1) + (p2 + p3);
        ushort4 pk;
        pk.x = f2bf_hw(p0); pk.y = f2bf_hw(p1); pk.z = f2bf_hw(p2); pk.w = f2bf_hw(p3);
        *(ushort4*)(base + (m * 32 + l31) * 256 + ((w * 64 + 16 * g + 8 * hi) ^ sw)) = pk;
    };

    bf8_t kA0, kA1;
    auto ldK = [&](int c) {
        const u16* kp = kh + ((size_t)bh * 64 + c * 4 + w) * 1024 + l31 * 16 + hi * 8;
        kA0 = *(const bf8_t*)kp;
        kA1 = *(const bf8_t*)(kp + 512);
    };

    {
        ldK(0);
        fx16 sA = __builtin_amdgcn_mfma_f32_32x32x16_bf16(kA0, qf[0][0], z16, 0, 0, 0);
        sA = __builtin_amdgcn_mfma_f32_32x32x16_bf16(kA1, qf[0][1], sA, 0, 0, 0);
        fx16 sB = __builtin_amdgcn_mfma_f32_32x32x16_bf16(kA0, qf[1][0], z16, 0, 0, 0);
        sB = __builtin_amdgcn_mfma_f32_32x32x16_bf16(kA1, qf[1][1], sB, 0, 0, 0);
        ldK(1);
        char* base0 = (char*)&Pb[0][0][0];
        #pragma unroll
        for (int g = 0; g < 4; ++g) finish(sA, 0, g, base0);
        #pragma unroll
        for (int g = 0; g < 4; ++g) finish(sB, 1, g, base0);
    }

    const u16* vpb = vhT + (((size_t)bh * 128) * 256 + w * 64 + l31) * 16 + hi * 8;
    bf8_t vb0 = *(const bf8_t*)vpb;
    bf8_t vb1 = *(const bf8_t*)(vpb + 512);

    int buf = 0;
    for (int c = 0; c < 16; ++c, buf ^= 1) {
        __syncthreads();
        const bool qn = (c < 15);
        fx16 sA, sB;
        if (qn) {
            sA = __builtin_amdgcn_mfma_f32_32x32x16_bf16(kA0, qf[0][0], z16, 0, 0, 0);
            sA = __builtin_amdgcn_mfma_f32_32x32x16_bf16(kA1, qf[0][1], sA, 0, 0, 0);
        }
        const char* pb = (const char*)&Pb[buf][0][0];
        char* wr = (char*)&Pb[buf ^ 1][0][0];
        const u16* vp = vpb + (size_t)c * 32768;
        #pragma unroll
        for (int ks = 0; ks < 8; ++ks) {
            bf8_t nv0 = *(const bf8_t*)(vp + (ks + 1) * 4096);
            bf8_t nv1 = *(const bf8_t*)(vp + (ks + 1) * 4096 + 512);
            bf8_t pa0 = *(const bf8_t*)(pb + l31 * 256        + ((ks * 32 + hi * 16) ^ sw));
            bf8_t pa1 = *(const bf8_t*)(pb + (32 + l31) * 256 + ((ks * 32 + hi * 16) ^ sw));
            __builtin_amdgcn_s_setprio(1);
            acc[0][0] = __builtin_amdgcn_mfma_f32_32x32x16_bf16(pa0, vb0, acc[0][0], 0, 0, 0);
            acc[0][1] = __builtin_amdgcn_mfma_f32_32x32x16_bf16(pa0, vb1, acc[0][1], 0, 0, 0);
            acc[1][0] = __builtin_amdgcn_mfma_f32_32x32x16_bf16(pa1, vb0, acc[1][0], 0, 0, 0);
            acc[1][1] = __builtin_amdgcn_mfma_f32_32x32x16_bf16(pa1, vb1, acc[1][1], 0, 0, 0);
            __builtin_amdgcn_s_setprio(0);
            if (qn) {
                if (ks < 4) {
                    finish(sA, 0, ks, wr);
                    if (ks == 3) {
                        sB = __builtin_amdgcn_mfma_f32_32x32x16_bf16(kA0, qf[1][0], z16, 0, 0, 0);
                        sB = __builtin_amdgcn_mfma_f32_32x32x16_bf16(kA1, qf[1][1], sB, 0, 0, 0);
                        if (c < 14) ldK(c + 2);
                    }
                } else {
                    finish(sB, 1, ks - 4, wr);
                }
            }
            vb0 = nv0; vb1 = nv1;
        }
    }

    #pragma unroll
    for (int m = 0; m < 2; ++m) {
        lsum[m] += __shfl_xor(lsum[m], 32, 64);
        if (hi == 0) lds_l[w][m * 32 + l31] = lsum[m];
    }
    __syncthreads();
    if (t < 64) lds_t[t] = lds_l[0][t] + lds_l[1][t] + lds_l[2][t] + lds_l[3][t];
    __syncthreads();

    #pragma unroll
    for (int mt = 0; mt < 2; ++mt)
        #pragma unroll
        for (int g = 0; g < 4; ++g) {
            f4_t lv = *(const f4_t*)&lds_t[mt * 32 + 8 * g + 4 * hi];
            #pragma unroll
            for (int j = 0; j < 4; ++j) {
                float inv = 1.0f / lv[j];
                int q = mt * 32 + 8 * g + 4 * hi + j;
                size_t rowbase = ((size_t)(b * 2048 + n0 + q)) * 2048 + h * 256 + w * 64;
                #pragma unroll
                for (int nt = 0; nt < 2; ++nt)
                    ao[rowbase + nt * 32 + l31] = f2bf_hw(acc[mt][nt][g * 4 + j] * inv);
            }
        }
}

extern "C" void kernel_launch(void* const* d_in, const int* in_sizes, int n_in,
                              void* d_out, int out_size, void* d_ws, size_t ws_size,
                              hipStream_t stream)
{
    u16* wsu = (u16*)d_ws;
    float* mk = (float*)(wsu + 64);              // 32 f32 (max key norm^2, int-atomics)

    // workspace layout (u16 units), ~95.7 MB (known-safe)
    const size_t CVT0 = 128;
    const size_t Y0   = CVT0 + SEG_TOT;          // y bf16 [8192,256]
    const size_t QH0  = Y0  + 2097152;
    const size_t KH0  = QH0 + 2097152;           // K tiled [bh][64][2][32][16]
    const size_t VT0  = KH0 + 2097152;           // V tiled [bh][128][256][16]
    const size_t AO0  = VT0 + 16777216;          // ao bf16 [8192][2048]
    const size_t X20  = AO0 + 16777216;          // x2 f32 [8192,256]
    // hbb bf16 [8192,1024] aliases AO0 (ao dead after merge GEMM)

    u16* cvt = wsu + CVT0;
    u16* y   = wsu + Y0;
    u16* qh  = wsu + QH0;
    u16* kh  = wsu + KH0;
    u16* vhT = wsu + VT0;
    u16* ao  = wsu + AO0;
    float* x2 = (float*)(wsu + X20);
    u16* hbb  = wsu + AO0;

    const u16* xc   = cvt + SEG_X;
    const u16* Wqkv = cvt + SEG_WQKV;   // transposed [2560][256]
    const u16* bqkv = cvt + SEG_BQKV;
    const u16* Wm   = cvt + SEG_WM;     // transposed [256][2048]
    const u16* bm   = cvt + SEG_BM;
    const u16* ln2g = cvt + SEG_LN2G;
    const u16* ln2b = cvt + SEG_LN2B;
    const u16* W1   = cvt + SEG_W1;     // transposed [1024][256]
    const u16* b1   = cvt + SEG_B1;
    const u16* W2   = cvt + SEG_W2;     // transposed [256][1024]
    const u16* b2   = cvt + SEG_B2;

    // unified prep: x+LN1 (8192) + biases/mkz (18) + weight transposes (416)
    prep_k<<<8626, 256, 0, stream>>>(
        d_in[0], d_in[1], d_in[2], d_in[3], d_in[4], d_in[5], d_in[6],
        d_in[7], d_in[8], d_in[9], d_in[10], d_in[11], d_in[12],
        cvt, y, (int*)mk);

    gemm_big<EP_QKV><<<dim3(2560 / 64, ROWS / 256), 256, 0, stream>>>(
        y, Wqkv, bqkv, nullptr, qh, kh, vhT, (int*)mk, 2560, 256);
    attn_k<<<1024, 256, 0, stream>>>(qh, kh, vhT, mk, ao);
    gemm_mfma<EP_MERGE><<<dim3(256 / 64, ROWS / 128), 256, 0, stream>>>(
        ao, Wm, bm, xc, x2, 256, 2048);
    ln_k<false><<<ROWS / 4, 256, 0, stream>>>(x2, ln2g, ln2b, y);
    gemm_big<EP_GELU><<<dim3(1024 / 64, ROWS / 256), 256, 0, stream>>>(
        y, W1, b1, hbb, nullptr, nullptr, nullptr, nullptr, 1024, 256);
    gemm_mfma<EP_FFN2><<<dim3(256 / 64, ROWS / 128), 256, 0, stream>>>(
        hbb, W2, b2, x2, d_out, 256, 1024);
}

// Round 14
// 273.069 us; speedup vs baseline: 1.7701x; 1.0796x over previous
//
#include <hip/hip_runtime.h>
#include <hip/hip_bf16.h>

typedef unsigned short u16;
typedef __attribute__((ext_vector_type(8))) short bf8_t;   // 8 bf16 (4 VGPR) MFMA A/B frag
typedef __attribute__((ext_vector_type(4))) float f4_t;    // MFMA C/D frag (16x16)
typedef __attribute__((ext_vector_type(16))) float fx16;   // MFMA C/D frag (32x32)

__device__ __forceinline__ float bf2f(u16 v) {
    union { unsigned u; float f; } c; c.u = ((unsigned)v) << 16; return c.f;
}
__device__ __forceinline__ u16 f2bf(float f) {  // RNE f32 -> bf16 (manual; cold paths)
    union { float f; unsigned u; } c; c.f = f;
    unsigned r = 0x7FFFu + ((c.u >> 16) & 1u);
    return (u16)((c.u + r) >> 16);
}
__device__ __forceinline__ u16 f2bf_hw(float f) {  // compiler fptrunc (RNE, packs to v_cvt_pk_bf16_f32)
    union { __hip_bfloat16 b; u16 u; } c; c.b = __float2bfloat16(f); return c.u;
}

// async global->LDS, 16B per lane. LDS dest is wave-uniform base + lane*16 (linear);
// global src is per-lane. Source chunk is pre-swizzled by caller (rule 21).
typedef __attribute__((address_space(3))) unsigned as3_u32;
typedef __attribute__((address_space(1))) const unsigned as1_u32;
__device__ __forceinline__ void gl16(const u16* g, u16* l) {
    __builtin_amdgcn_global_load_lds((as1_u32*)(const void*)g, (as3_u32*)(void*)l, 16, 0, 0);
}

#define B_   4
#define N_   2048
#define INC  256
#define H_   8
#define ROWS 8192

// canonical (bf16) segment offsets within cvt, u16 units. Weights stored TRANSPOSED: Bt[n][k].
#define SEG_X     0
#define SEG_LN1G  2097152
#define SEG_LN1B  2097408
#define SEG_WQKV  2097664
#define SEG_BQKV  2753024
#define SEG_WM    2755584
#define SEG_BM    3279872
#define SEG_LN2G  3280128
#define SEG_LN2B  3280384
#define SEG_W1    3280640
#define SEG_B1    3542784
#define SEG_W2    3543808
#define SEG_B2    3805952
#define SEG_TOT   3806208

// ---------------- self-sniff helper: detect fp32 vs bf16 inputs from x[0..1023] ----------
__device__ __forceinline__ int sniff_flag(const void* x0, int t, int* sh) {
    if (t == 0) *sh = 0;
    __syncthreads();
    int bad = 0;
    #pragma unroll
    for (int k2 = 0; k2 < 4; ++k2) {
        float v = bf2f(((const u16*)x0)[t * 4 + k2]);
        if (!(fabsf(v) < 1e10f)) bad = 1;
    }
    if (bad) atomicOr(sh, 1);
    __syncthreads();
    return *sh;   // 1 => fp32 inputs, 0 => bf16
}

// ---------------- unified prep: x+LN1, biases, mkz zero, weight transposes --------------
__global__ __launch_bounds__(256) void prep_k(
    const void* p0, const void* p1, const void* p2, const void* p3, const void* p4,
    const void* p5, const void* p6, const void* p7, const void* p8, const void* p9,
    const void* p10, const void* p11, const void* p12,
    u16* __restrict__ dst, u16* __restrict__ y, int* __restrict__ mkz)
{
    const int t = threadIdx.x;
    const int blk = blockIdx.x;
    __shared__ int sflag;
    const int flag = sniff_flag(p0, t, &sflag);

    if (blk < 8192) {         // x row: convert + fused LN1
        const int i = blk * 256 + t;
        float v = flag ? ((const float*)p0)[i] : bf2f(((const u16*)p0)[i]);
        dst[i] = f2bf_hw(v);
        float s = v, s2 = v * v;
        #pragma unroll
        for (int d = 1; d < 64; d <<= 1) {
            s  += __shfl_xor(s,  d, 64);
            s2 += __shfl_xor(s2, d, 64);
        }
        __shared__ float rs[8];
        int w = t >> 6;
        if ((t & 63) == 0) { rs[w] = s; rs[4 + w] = s2; }
        __syncthreads();
        s  = rs[0] + rs[1] + rs[2] + rs[3];
        s2 = rs[4] + rs[5] + rs[6] + rs[7];
        float mean = s * (1.0f / INC);
        float var  = s2 * (1.0f / INC) - mean * mean;
        float inv  = rsqrtf(var + 1e-5f);
        float g  = flag ? ((const float*)p1)[t] : bf2f(((const u16*)p1)[t]);
        float bb = flag ? ((const float*)p2)[t] : bf2f(((const u16*)p2)[t]);
        y[i] = f2bf_hw((v - mean) * inv * g + bb);
        return;
    }

    if (blk < 8210) {         // bias segments
        if (blk == 8192 && t < 32) mkz[t] = 0;
        const int elem = (blk - 8192) * 256 + t;   // 0..4607 over concatenated bias segs
        const void* p; int j; size_t doff;
        if      (elem < 2560) { p = p4;  j = elem;        doff = SEG_BQKV + j; }
        else if (elem < 2816) { p = p6;  j = elem - 2560; doff = SEG_BM   + j; }
        else if (elem < 3072) { p = p7;  j = elem - 2816; doff = SEG_LN2G + j; }
        else if (elem < 3328) { p = p8;  j = elem - 3072; doff = SEG_LN2B + j; }
        else if (elem < 4352) { p = p10; j = elem - 3328; doff = SEG_B1   + j; }
        else                  { p = p12; j = elem - 4352; doff = SEG_B2   + j; }
        dst[doff] = flag ? f2bf(((const float*)p)[j]) : ((const u16*)p)[j];
        return;
    }

    // weight transpose: Wqkv 160 tiles, Wm 128, W1 64, W2 64
    const int blk2 = blk - 8210;
    const void* W; int Kd, Nd, kt, nt; size_t seg;
    if (blk2 < 160)      { W = p3;  Kd = 256;  Nd = 2560; kt = blk2 / 40;  nt = blk2 % 40;  seg = SEG_WQKV; }
    else if (blk2 < 288) { int i2 = blk2 - 160; W = p5;  Kd = 2048; Nd = 256;  kt = i2 >> 2;  nt = i2 & 3;  seg = SEG_WM; }
    else if (blk2 < 352) { int i2 = blk2 - 288; W = p9;  Kd = 256;  Nd = 1024; kt = i2 >> 4;  nt = i2 & 15; seg = SEG_W1; }
    else                 { int i2 = blk2 - 352; W = p11; Kd = 1024; Nd = 256;  kt = i2 >> 2;  nt = i2 & 3;  seg = SEG_W2; }
    const int k0 = kt * 64, n0 = nt * 64;

    __shared__ u16 Tl[64][66];
    #pragma unroll
    for (int p = 0; p < 16; ++p) {
        int idx = t + p * 256;
        int r = idx >> 6, c = idx & 63;
        size_t si = (size_t)(k0 + r) * Nd + n0 + c;
        Tl[r][c] = flag ? f2bf(((const float*)W)[si]) : ((const u16*)W)[si];
    }
    __syncthreads();
    u16* dp = dst + seg;
    #pragma unroll
    for (int p = 0; p < 8; ++p) {
        int idx = t + p * 256;
        int rn = idx >> 5, ck = (idx & 31) * 2;
        ushort2 v; v.x = Tl[ck][rn]; v.y = Tl[ck + 1][rn];
        *(ushort2*)(dp + (size_t)(n0 + rn) * Kd + k0 + ck) = v;   // Wt[n][k] = W[k][n]
    }
}

// ---------------- LayerNorm (f32 input), one wave per row, 4 rows/block ----------------
template<bool BF16IN>
__global__ __launch_bounds__(256) void ln_k(const void* __restrict__ xp,
        const u16* __restrict__ g, const u16* __restrict__ b, u16* __restrict__ y)
{
    int row  = blockIdx.x * 4 + (threadIdx.x >> 6);
    int lane = threadIdx.x & 63;
    int c0   = lane * 4;
    float v[4];
    if (BF16IN) {
        ushort4 u = *(const ushort4*)((const u16*)xp + (size_t)row * INC + c0);
        v[0] = bf2f(u.x); v[1] = bf2f(u.y); v[2] = bf2f(u.z); v[3] = bf2f(u.w);
    } else {
        float4 f = *(const float4*)((const float*)xp + (size_t)row * INC + c0);
        v[0] = f.x; v[1] = f.y; v[2] = f.z; v[3] = f.w;
    }
    float s = v[0] + v[1] + v[2] + v[3];
    float s2 = v[0]*v[0] + v[1]*v[1] + v[2]*v[2] + v[3]*v[3];
    #pragma unroll
    for (int d = 1; d < 64; d <<= 1) {
        s  += __shfl_xor(s,  d, 64);
        s2 += __shfl_xor(s2, d, 64);
    }
    float mean = s * (1.0f / INC);
    float var  = s2 * (1.0f / INC) - mean * mean;
    float inv  = rsqrtf(var + 1e-5f);
    ushort4 gv = *(const ushort4*)(g + c0);
    ushort4 bv = *(const ushort4*)(b + c0);
    ushort4 o;
    o.x = f2bf_hw((v[0] - mean) * inv * bf2f(gv.x) + bf2f(bv.x));
    o.y = f2bf_hw((v[1] - mean) * inv * bf2f(gv.y) + bf2f(bv.y));
    o.z = f2bf_hw((v[2] - mean) * inv * bf2f(gv.z) + bf2f(bv.z));
    o.w = f2bf_hw((v[3] - mean) * inv * bf2f(gv.w) + bf2f(bv.w));
    *(ushort4*)(y + (size_t)row * INC + c0) = o;
}

enum { EP_QKV = 0, EP_MERGE = 1, EP_GELU = 2, EP_FFN2 = 3 };

// ---------------- big-tile GEMM (QKV / GELU): block 256x64, BK=64, double-buffered -----
// R14: m97 2-phase schedule -- stage(t+1) issued BEFORE compute(t); ONE barrier per
// K-step (its implicit vmcnt(0) drains the prefetch). LDS 2x40KB -> 2 blocks/CU.
// MFMA order identical to R13 -> bit-identical results.
template<int MODE>
__global__ __launch_bounds__(256) void gemm_big(
    const u16* __restrict__ A, const u16* __restrict__ Bt,
    const u16* __restrict__ bias, void* __restrict__ outp,
    u16* __restrict__ qh, u16* __restrict__ kh, u16* __restrict__ vh,
    int* __restrict__ mkz, int N, int K)
{
    const int t = threadIdx.x;
    const int w = t >> 6, lane = t & 63;
    const int l15 = lane & 15, quad = lane >> 4;
    const int col0 = blockIdx.x * 64;
    const int row0 = blockIdx.y * 256;
    const int lr = lane >> 3;                  // row within 8-row staging group
    const int sc = ((lane & 7) ^ lr) * 8;      // pre-swizzled source chunk (u16 units)

    __shared__ __align__(16) u16 Sb[40960];    // 80KB: 2 x (A[256][64] + B[64][64])

    auto stage = [&](int cur, int k0) {
        u16* Al = Sb + cur * 20480;
        u16* Bl = Al + 16384;
        #pragma unroll
        for (int i = 0; i < 8; ++i) {
            int r = w * 64 + i * 8;
            gl16(A + (size_t)(row0 + r + lr) * K + k0 + sc, Al + r * 64);
        }
        gl16(Bt + (size_t)(col0 + w * 16 + lr) * K + k0 + sc,     Bl + (w * 16) * 64);
        gl16(Bt + (size_t)(col0 + w * 16 + 8 + lr) * K + k0 + sc, Bl + (w * 16 + 8) * 64);
    };

    f4_t acc[4][4];
    #pragma unroll
    for (int mi = 0; mi < 4; ++mi)
        #pragma unroll
        for (int ni = 0; ni < 4; ++ni)
            acc[mi][ni] = (f4_t){0.f, 0.f, 0.f, 0.f};

    const int nt = K >> 6;
    int cur = 0;
    stage(0, 0);
    for (int t2 = 0; t2 < nt; ++t2, cur ^= 1) {
        __syncthreads();                       // drains stage(t2); fences prior reads
        if (t2 + 1 < nt) stage(cur ^ 1, (t2 + 1) << 6);
        const u16* Al = Sb + cur * 20480;
        const u16* Bl = Al + 16384;
        #pragma unroll
        for (int kc = 0; kc < 2; ++kc) {
            bf8_t a[4], bb[4];
            #pragma unroll
            for (int mi = 0; mi < 4; ++mi) {
                int row = w * 64 + mi * 16 + l15;
                a[mi] = *(const bf8_t*)(Al + row * 64 + ((kc * 4 + quad) ^ (row & 7)) * 8);
            }
            #pragma unroll
            for (int ni = 0; ni < 4; ++ni) {
                int row = ni * 16 + l15;
                bb[ni] = *(const bf8_t*)(Bl + row * 64 + ((kc * 4 + quad) ^ (row & 7)) * 8);
            }
            #pragma unroll
            for (int ni = 0; ni < 4; ++ni)
                #pragma unroll
                for (int mi = 0; mi < 4; ++mi)
                    acc[mi][ni] = __builtin_amdgcn_mfma_f32_16x16x32_bf16(
                        a[mi], bb[ni], acc[mi][ni], 0, 0, 0);
        }
    }
    __syncthreads();                           // guard epilogue's reuse of Sb
    const int mrow = row0 + w * 64;

    if (MODE == EP_QKV) {
        if (col0 >= 512) {
            // V: transpose 256 tokens x 64 chans through LDS -> vh tiled [bh][tok/16][vc256][tok%16]
            u16 (*Ts)[268] = (u16(*)[268])Sb;
            #pragma unroll
            for (int mi = 0; mi < 4; ++mi)
                #pragma unroll
                for (int ni = 0; ni < 4; ++ni) {
                    float bz = bf2f(bias[col0 + ni * 16 + l15]);
                    #pragma unroll
                    for (int r = 0; r < 4; ++r)
                        Ts[ni * 16 + l15][w * 64 + mi * 16 + quad * 4 + r] =
                            f2bf_hw(acc[mi][ni][r] + bz);
                }
            __syncthreads();
            int vcg = col0 - 512;
            int hh  = vcg >> 8;
            int bb2 = row0 >> 11, nb = row0 & 2047;
            int bhh = bb2 * 8 + hh;
            int tok4 = t & 3, cl = (t >> 2) & 63;
            int vc = (vcg & 255) + cl;
            #pragma unroll
            for (int kb = 0; kb < 16; ++kb) {
                u16* dp = vh + (((size_t)bhh * 128 + ((nb >> 4) + kb)) * 256 + vc) * 16 + tok4 * 4;
                *(ushort4*)dp = *(const ushort4*)&Ts[cl][kb * 16 + tok4 * 4];
            }
        } else if (col0 < 256) {   // Q cols
            #pragma unroll
            for (int mi = 0; mi < 4; ++mi)
                #pragma unroll
                for (int r = 0; r < 4; ++r) {
                    int rg = mrow + mi * 16 + quad * 4 + r;
                    int bb2 = rg >> 11, n = rg & 2047;
                    #pragma unroll
                    for (int ni = 0; ni < 4; ++ni) {
                        int col = col0 + ni * 16 + l15;
                        float v = acc[mi][ni][r] + bf2f(bias[col]);
                        qh[(((size_t)(bb2 * 8 + (col >> 5))) * 2048 + n) * 32 + (col & 31)] = f2bf_hw(v);
                    }
                }
        } else {                   // K cols: store tiled + fused per-head max norm^2
            const int hA  = (col0 - 256) >> 5;
            const int bb2 = row0 >> 11;
            float mxA = 0.f, mxB = 0.f;
            #pragma unroll
            for (int mi = 0; mi < 4; ++mi)
                #pragma unroll
                for (int r = 0; r < 4; ++r) {
                    int rg = mrow + mi * 16 + quad * 4 + r;
                    int n = rg & 2047;
                    float vv[4];
                    #pragma unroll
                    for (int ni = 0; ni < 4; ++ni) {
                        int col = col0 + ni * 16 + l15;
                        float v = acc[mi][ni][r] + bf2f(bias[col]);
                        vv[ni] = v;
                        int c2 = col - 256;
                        int hd = c2 >> 5, ch = c2 & 31;
                        kh[(((size_t)(bb2 * 8 + hd) * 64 + (n >> 5)) * 2 + (ch >> 4)) * 512
                           + (n & 31) * 16 + (ch & 15)] = f2bf_hw(v);
                    }
                    float sA = vv[0] * vv[0] + vv[1] * vv[1];
                    float sB = vv[2] * vv[2] + vv[3] * vv[3];
                    #pragma unroll
                    for (int d = 1; d < 16; d <<= 1) {
                        sA += __shfl_xor(sA, d, 64);
                        sB += __shfl_xor(sB, d, 64);
                    }
                    mxA = fmaxf(mxA, sA);
                    mxB = fmaxf(mxB, sB);
                }
            if ((lane & 15) == 0) {
                atomicMax(mkz + bb2 * 8 + hA,     __float_as_int(mxA));
                atomicMax(mkz + bb2 * 8 + hA + 1, __float_as_int(mxB));
            }
        }
    } else {   // EP_GELU: exact gelu -> LDS retile -> coalesced bf16 stores
        u16 (*Ts2)[72] = (u16(*)[72])Sb;
        float bz[4];
        #pragma unroll
        for (int ni = 0; ni < 4; ++ni) bz[ni] = bf2f(bias[col0 + ni * 16 + l15]);
        #pragma unroll
        for (int mi = 0; mi < 4; ++mi)
            #pragma unroll
            for (int ni = 0; ni < 4; ++ni)
                #pragma unroll
                for (int r = 0; r < 4; ++r) {
                    float v = acc[mi][ni][r] + bz[ni];
                    v = 0.5f * v * (1.0f + erff(v * 0.70710678118654752f));
                    Ts2[w * 64 + mi * 16 + quad * 4 + r][ni * 16 + l15] = f2bf_hw(v);
                }
        __syncthreads();
        const int rl0 = t >> 3, c8 = (t & 7) * 8;
        #pragma unroll
        for (int p = 0; p < 8; ++p) {
            int rl = rl0 + p * 32;
            *(bf8_t*)((u16*)outp + (size_t)(row0 + rl) * N + col0 + c8) =
                *(const bf8_t*)&Ts2[rl][c8];
        }
    }
}

// ---------------- MFMA GEMM (MERGE / FFN2): block 128x64, BK=64, double-buffered -------
template<int MODE>
__global__ __launch_bounds__(256) void gemm_mfma(
    const u16* __restrict__ A, const u16* __restrict__ Bt,
    const u16* __restrict__ bias, const void* __restrict__ res,
    void* __restrict__ outp, int N, int K)
{
    const int t = threadIdx.x;
    const int w = t >> 6, lane = t & 63;
    const int l15 = lane & 15, quad = lane >> 4;
    const int col0 = blockIdx.x * 64;
    const int row0 = blockIdx.y * 128;
    const int lr = lane >> 3;
    const int sc = ((lane & 7) ^ lr) * 8;

    __shared__ __align__(16) u16 Sm[24576];     // 48KB: 2 x (A[128][64] + B[64][64]); Tf aliases
    float (*Tf)[68] = (float(*)[68])Sm;

    auto stage = [&](int cur, int k0) {
        u16* Al = Sm + cur * 12288;
        u16* Bl = Al + 8192;
        #pragma unroll
        for (int i = 0; i < 4; ++i) {
            int r = w * 32 + i * 8;
            gl16(A + (size_t)(row0 + r + lr) * K + k0 + sc, Al + r * 64);
        }
        gl16(Bt + (size_t)(col0 + w * 16 + lr) * K + k0 + sc,     Bl + (w * 16) * 64);
        gl16(Bt + (size_t)(col0 + w * 16 + 8 + lr) * K + k0 + sc, Bl + (w * 16 + 8) * 64);
    };

    f4_t acc[2][4];
    #pragma unroll
    for (int mi = 0; mi < 2; ++mi)
        #pragma unroll
        for (int ni = 0; ni < 4; ++ni)
            acc[mi][ni] = (f4_t){0.f, 0.f, 0.f, 0.f};

    const int nt = K >> 6;
    int cur = 0;
    stage(0, 0);
    for (int t2 = 0; t2 < nt; ++t2, cur ^= 1) {
        __syncthreads();
        if (t2 + 1 < nt) stage(cur ^ 1, (t2 + 1) << 6);
        const u16* Al = Sm + cur * 12288;
        const u16* Bl = Al + 8192;
        #pragma unroll
        for (int kc = 0; kc < 2; ++kc) {
            bf8_t a[2], bb[4];
            #pragma unroll
            for (int mi = 0; mi < 2; ++mi) {
                int row = w * 32 + mi * 16 + l15;
                a[mi] = *(const bf8_t*)(Al + row * 64 + ((kc * 4 + quad) ^ (row & 7)) * 8);
            }
            #pragma unroll
            for (int ni = 0; ni < 4; ++ni) {
                int row = ni * 16 + l15;
                bb[ni] = *(const bf8_t*)(Bl + row * 64 + ((kc * 4 + quad) ^ (row & 7)) * 8);
            }
            #pragma unroll
            for (int ni = 0; ni < 4; ++ni)
                #pragma unroll
                for (int mi = 0; mi < 2; ++mi)
                    acc[mi][ni] = __builtin_amdgcn_mfma_f32_16x16x32_bf16(
                        a[mi], bb[ni], acc[mi][ni], 0, 0, 0);
        }
    }
    __syncthreads();                            // guard Tf's reuse of the staging region

    float bz[4];
    #pragma unroll
    for (int ni = 0; ni < 4; ++ni) bz[ni] = bf2f(bias[col0 + ni * 16 + l15]);
    #pragma unroll
    for (int mi = 0; mi < 2; ++mi)
        #pragma unroll
        for (int ni = 0; ni < 4; ++ni)
            #pragma unroll
            for (int r = 0; r < 4; ++r)
                Tf[w * 32 + mi * 16 + quad * 4 + r][ni * 16 + l15] = acc[mi][ni][r] + bz[ni];
    __syncthreads();

    const int rl0 = t >> 4, c4 = (t & 15) * 4;
    #pragma unroll
    for (int p = 0; p < 8; ++p) {
        int rl = rl0 + p * 16;
        float4 v = *(const float4*)&Tf[rl][c4];
        size_t base = (size_t)(row0 + rl) * N + col0 + c4;
        if (MODE == EP_MERGE) {          // + x (bf16 residual) -> f32 x2
            ushort4 rv = *(const ushort4*)((const u16*)res + base);
            v.x += bf2f(rv.x); v.y += bf2f(rv.y); v.z += bf2f(rv.z); v.w += bf2f(rv.w);
        } else {                          // EP_FFN2: + x2 (f32 residual) -> fp32 d_out
            float4 rv = *(const float4*)((const float*)res + base);
            v.x += rv.x; v.y += rv.y; v.z += rv.z; v.w += rv.w;
        }
        *(float4*)((float*)outp + base) = v;
    }
}

// ---------------- MFMA flash attention, 32x32x16, software-pipelined (R8-proven) ----------
__global__ __launch_bounds__(256) void attn_k(
    const u16* __restrict__ qh, const u16* __restrict__ kh,
    const u16* __restrict__ vhT, const float* __restrict__ mk2,
    u16* __restrict__ ao)
{
    const int t = threadIdx.x;
    const int w = t >> 6, lane = t & 63;
    const int l31 = lane & 31, hi = lane >> 5;
    const int id = blockIdx.x;
    const int qt = (id >> 3) & 31;
    const int bh = (id >> 8) * 8 + (id & 7);   // id%8 = XCD affinity per (b,h)
    const int b  = bh >> 3, h = bh & 7;
    const int n0 = qt * 64;
    const float SCALE = 0.17677669529663687f;  // 1/sqrt(32)
    const int sw = (l31 & 7) << 4;             // LDS XOR swizzle (byte bits 4-6)

    __shared__ __align__(16) u16 Pb[2][64][128];  // [buf][q][key], stride 256B, XOR-swizzled
    __shared__ float lds_l[4][64];
    __shared__ float lds_t[64];

    bf8_t qf[2][2];
    #pragma unroll
    for (int m = 0; m < 2; ++m)
        #pragma unroll
        for (int ks = 0; ks < 2; ++ks)
            qf[m][ks] = *(const bf8_t*)(qh + ((size_t)bh * 2048 + n0 + m * 32 + l31) * 32
                                        + ks * 16 + hi * 8);

    float mrow[2];
    #pragma unroll
    for (int m = 0; m < 2; ++m) {
        float q2 = 0.f;
        #pragma unroll
        for (int ks = 0; ks < 2; ++ks)
            #pragma unroll
            for (int i = 0; i < 8; ++i) {
                float qv = bf2f((u16)qf[m][ks][i]); q2 += qv * qv;
            }
        q2 += __shfl_xor(q2, 32, 64);
        mrow[m] = SCALE * sqrtf(q2 * mk2[bh]);
    }

    fx16 acc[2][2];
    #pragma unroll
    for (int a1 = 0; a1 < 2; ++a1)
        #pragma unroll
        for (int a2 = 0; a2 < 2; ++a2)
            #pragma unroll
            for (int e = 0; e < 16; ++e) acc[a1][a2][e] = 0.f;
    float lsum[2] = {0.f, 0.f};

    fx16 z16;
    #pragma unroll
    for (int e = 0; e < 16; ++e) z16[e] = 0.f;

    auto finish = [&](const fx16& s, int m, int g, char* base) {
        float p0 = __expf(fmaf(s[4 * g + 0], SCALE, -mrow[m]));
        float p1 = __expf(fmaf(s[4 * g + 1], SCALE, -mrow[m]));
        float p2 = __expf(fmaf(s[4 * g + 2], SCALE, -mrow[m]));
        float p3 = __expf(fmaf(s[4 * g + 3], SCALE, -mrow[m]));
        lsum[m] += (p0 + p1) + (p2 + p3);
        ushort4 pk;
        pk.x = f2bf_hw(p0); pk.y = f2bf_hw(p1); pk.z = f2bf_hw(p2); pk.w = f2bf_hw(p3);
        *(ushort4*)(base + (m * 32 + l31) * 256 + ((w * 64 + 16 * g + 8 * hi) ^ sw)) = pk;
    };

    bf8_t kA0, kA1;
    auto ldK = [&](int c) {
        const u16* kp = kh + ((size_t)bh * 64 + c * 4 + w) * 1024 + l31 * 16 + hi * 8;
        kA0 = *(const bf8_t*)kp;
        kA1 = *(const bf8_t*)(kp + 512);
    };

    {
        ldK(0);
        fx16 sA = __builtin_amdgcn_mfma_f32_32x32x16_bf16(kA0, qf[0][0], z16, 0, 0, 0);
        sA = __builtin_amdgcn_mfma_f32_32x32x16_bf16(kA1, qf[0][1], sA, 0, 0, 0);
        fx16 sB = __builtin_amdgcn_mfma_f32_32x32x16_bf16(kA0, qf[1][0], z16, 0, 0, 0);
        sB = __builtin_amdgcn_mfma_f32_32x32x16_bf16(kA1, qf[1][1], sB, 0, 0, 0);
        ldK(1);
        char* base0 = (char*)&Pb[0][0][0];
        #pragma unroll
        for (int g = 0; g < 4; ++g) finish(sA, 0, g, base0);
        #pragma unroll
        for (int g = 0; g < 4; ++g) finish(sB, 1, g, base0);
    }

    const u16* vpb = vhT + (((size_t)bh * 128) * 256 + w * 64 + l31) * 16 + hi * 8;
    bf8_t vb0 = *(const bf8_t*)vpb;
    bf8_t vb1 = *(const bf8_t*)(vpb + 512);

    int buf = 0;
    for (int c = 0; c < 16; ++c, buf ^= 1) {
        __syncthreads();
        const bool qn = (c < 15);
        fx16 sA, sB;
        if (qn) {
            sA = __builtin_amdgcn_mfma_f32_32x32x16_bf16(kA0, qf[0][0], z16, 0, 0, 0);
            sA = __builtin_amdgcn_mfma_f32_32x32x16_bf16(kA1, qf[0][1], sA, 0, 0, 0);
        }
        const char* pb = (const char*)&Pb[buf][0][0];
        char* wr = (char*)&Pb[buf ^ 1][0][0];
        const u16* vp = vpb + (size_t)c * 32768;
        #pragma unroll
        for (int ks = 0; ks < 8; ++ks) {
            bf8_t nv0 = *(const bf8_t*)(vp + (ks + 1) * 4096);
            bf8_t nv1 = *(const bf8_t*)(vp + (ks + 1) * 4096 + 512);
            bf8_t pa0 = *(const bf8_t*)(pb + l31 * 256        + ((ks * 32 + hi * 16) ^ sw));
            bf8_t pa1 = *(const bf8_t*)(pb + (32 + l31) * 256 + ((ks * 32 + hi * 16) ^ sw));
            __builtin_amdgcn_s_setprio(1);
            acc[0][0] = __builtin_amdgcn_mfma_f32_32x32x16_bf16(pa0, vb0, acc[0][0], 0, 0, 0);
            acc[0][1] = __builtin_amdgcn_mfma_f32_32x32x16_bf16(pa0, vb1, acc[0][1], 0, 0, 0);
            acc[1][0] = __builtin_amdgcn_mfma_f32_32x32x16_bf16(pa1, vb0, acc[1][0], 0, 0, 0);
            acc[1][1] = __builtin_amdgcn_mfma_f32_32x32x16_bf16(pa1, vb1, acc[1][1], 0, 0, 0);
            __builtin_amdgcn_s_setprio(0);
            if (qn) {
                if (ks < 4) {
                    finish(sA, 0, ks, wr);
                    if (ks == 3) {
                        sB = __builtin_amdgcn_mfma_f32_32x32x16_bf16(kA0, qf[1][0], z16, 0, 0, 0);
                        sB = __builtin_amdgcn_mfma_f32_32x32x16_bf16(kA1, qf[1][1], sB, 0, 0, 0);
                        if (c < 14) ldK(c + 2);
                    }
                } else {
                    finish(sB, 1, ks - 4, wr);
                }
            }
            vb0 = nv0; vb1 = nv1;
        }
    }

    #pragma unroll
    for (int m = 0; m < 2; ++m) {
        lsum[m] += __shfl_xor(lsum[m], 32, 64);
        if (hi == 0) lds_l[w][m * 32 + l31] = lsum[m];
    }
    __syncthreads();
    if (t < 64) lds_t[t] = lds_l[0][t] + lds_l[1][t] + lds_l[2][t] + lds_l[3][t];
    __syncthreads();

    #pragma unroll
    for (int mt = 0; mt < 2; ++mt)
        #pragma unroll
        for (int g = 0; g < 4; ++g) {
            f4_t lv = *(const f4_t*)&lds_t[mt * 32 + 8 * g + 4 * hi];
            #pragma unroll
            for (int j = 0; j < 4; ++j) {
                float inv = 1.0f / lv[j];
                int q = mt * 32 + 8 * g + 4 * hi + j;
                size_t rowbase = ((size_t)(b * 2048 + n0 + q)) * 2048 + h * 256 + w * 64;
                #pragma unroll
                for (int nt2 = 0; nt2 < 2; ++nt2)
                    ao[rowbase + nt2 * 32 + l31] = f2bf_hw(acc[mt][nt2][g * 4 + j] * inv);
            }
        }
}

extern "C" void kernel_launch(void* const* d_in, const int* in_sizes, int n_in,
                              void* d_out, int out_size, void* d_ws, size_t ws_size,
                              hipStream_t stream)
{
    u16* wsu = (u16*)d_ws;
    float* mk = (float*)(wsu + 64);              // 32 f32 (max key norm^2, int-atomics)

    // workspace layout (u16 units), ~95.7 MB (known-safe)
    const size_t CVT0 = 128;
    const size_t Y0   = CVT0 + SEG_TOT;          // y bf16 [8192,256]
    const size_t QH0  = Y0  + 2097152;
    const size_t KH0  = QH0 + 2097152;           // K tiled [bh][64][2][32][16]
    const size_t VT0  = KH0 + 2097152;           // V tiled [bh][128][256][16]
    const size_t AO0  = VT0 + 16777216;          // ao bf16 [8192][2048]
    const size_t X20  = AO0 + 16777216;          // x2 f32 [8192,256]
    // hbb bf16 [8192,1024] aliases AO0 (ao dead after merge GEMM)

    u16* cvt = wsu + CVT0;
    u16* y   = wsu + Y0;
    u16* qh  = wsu + QH0;
    u16* kh  = wsu + KH0;
    u16* vhT = wsu + VT0;
    u16* ao  = wsu + AO0;
    float* x2 = (float*)(wsu + X20);
    u16* hbb  = wsu + AO0;

    const u16* xc   = cvt + SEG_X;
    const u16* Wqkv = cvt + SEG_WQKV;   // transposed [2560][256]
    const u16* bqkv = cvt + SEG_BQKV;
    const u16* Wm   = cvt + SEG_WM;     // transposed [256][2048]
    const u16* bm   = cvt + SEG_BM;
    const u16* ln2g = cvt + SEG_LN2G;
    const u16* ln2b = cvt + SEG_LN2B;
    const u16* W1   = cvt + SEG_W1;     // transposed [1024][256]
    const u16* b1   = cvt + SEG_B1;
    const u16* W2   = cvt + SEG_W2;     // transposed [256][1024]
    const u16* b2   = cvt + SEG_B2;

    // unified prep: x+LN1 (8192) + biases/mkz (18) + weight transposes (416)
    prep_k<<<8626, 256, 0, stream>>>(
        d_in[0], d_in[1], d_in[2], d_in[3], d_in[4], d_in[5], d_in[6],
        d_in[7], d_in[8], d_in[9], d_in[10], d_in[11], d_in[12],
        cvt, y, (int*)mk);

    gemm_big<EP_QKV><<<dim3(2560 / 64, ROWS / 256), 256, 0, stream>>>(
        y, Wqkv, bqkv, nullptr, qh, kh, vhT, (int*)mk, 2560, 256);
    attn_k<<<1024, 256, 0, stream>>>(qh, kh, vhT, mk, ao);
    gemm_mfma<EP_MERGE><<<dim3(256 / 64, ROWS / 128), 256, 0, stream>>>(
        ao, Wm, bm, xc, x2, 256, 2048);
    ln_k<false><<<ROWS / 4, 256, 0, stream>>>(x2, ln2g, ln2b, y);
    gemm_big<EP_GELU><<<dim3(1024 / 64, ROWS / 256), 256, 0, stream>>>(
        y, W1, b1, hbb, nullptr, nullptr, nullptr, nullptr, 1024, 256);
    gemm_mfma<EP_FFN2><<<dim3(256 / 64, ROWS / 128), 256, 0, stream>>>(
        hbb, W2, b2, x2, d_out, 256, 1024);
}